// Round 10
// baseline (331.269 us; speedup 1.0000x reference)
//
#include <hip/hip_runtime.h>
#include <math.h>

// TGCN: bf16 feature-space GCN aggregation (fp32 accum) -> single fused GRU
// kernel (z,r,hq,ht in one pass; B-slice in REGISTERS per wave, A in LDS).
// CSR-by-dst built with ZERO global atomics (device-scope atomics execute at
// the HBM/fabric side on gfx950 -> each one is an HBM write transaction):
//   LDS-privatized (range x chunk) histogram -> partial counts/weights (plain
//   coalesced stores) -> reduce -> scan -> per-chunk offset col-scan ->
//   fill with packed-ushort LDS ranks.

#define HD 128
#define RBITS 13
#define RSIZE 8192          // nodes per histogram range (64KB LDS)
#define MAXN_HALF 25088     // packed-cursor LDS words (covers N <= 50176)

typedef __attribute__((ext_vector_type(8))) short short8;
typedef __attribute__((ext_vector_type(4))) float f32x4;

__device__ __forceinline__ ushort f2bf(float f) {
    union { float f; unsigned u; } v; v.f = f;
    unsigned r = (v.u + 0x7FFFu + ((v.u >> 16) & 1u)) >> 16;
    return (ushort)r;
}
__device__ __forceinline__ float bf2f(ushort h) {
    union { unsigned u; float f; } v; v.u = ((unsigned)h) << 16;
    return v.f;
}
__device__ __forceinline__ float bflo(unsigned u) {
    union { unsigned u; float f; } v; v.u = u << 16; return v.f;
}
__device__ __forceinline__ float bfhi(unsigned u) {
    union { unsigned u; float f; } v; v.u = u & 0xFFFF0000u; return v.f;
}
__device__ __forceinline__ float fast_sigmoid(float x) {
    return 1.0f / (1.0f + __expf(-x));
}
__device__ __forceinline__ float fast_tanh(float x) {
    float e = __expf(-2.0f * fabsf(x));
    float m = (1.0f - e) / (1.0f + e);
    return copysignf(m, x);
}

// nf -> bf16, h0 -> bf16 (vectorized)
__global__ void prep_kernel(const float* __restrict__ nf, const float* __restrict__ h0,
                            ushort* __restrict__ nfb, ushort* __restrict__ h0b, int n) {
    int idx = blockIdx.x * 256 + threadIdx.x;
    int total8 = n * (HD / 8);
    if (idx < total8) {
        const float4* p = (const float4*)(nf + (size_t)idx * 8);
        float4 x = p[0], y = p[1];
        short8 o;
        o[0] = (short)f2bf(x.x); o[1] = (short)f2bf(x.y);
        o[2] = (short)f2bf(x.z); o[3] = (short)f2bf(x.w);
        o[4] = (short)f2bf(y.x); o[5] = (short)f2bf(y.y);
        o[6] = (short)f2bf(y.z); o[7] = (short)f2bf(y.w);
        *(short8*)(nfb + (size_t)idx * 8) = o;
        const float4* q = (const float4*)(h0 + (size_t)idx * 8);
        float4 a = q[0], b = q[1];
        short8 o2;
        o2[0] = (short)f2bf(a.x); o2[1] = (short)f2bf(a.y);
        o2[2] = (short)f2bf(a.z); o2[3] = (short)f2bf(a.w);
        o2[4] = (short)f2bf(b.x); o2[5] = (short)f2bf(b.y);
        o2[6] = (short)f2bf(b.z); o2[7] = (short)f2bf(b.w);
        *(short8*)(h0b + (size_t)idx * 8) = o2;
    }
}

// LDS-privatized histogram. Block (r = bid%NR, c = bid/NR): counts/weights of
// dst in range r over edge chunk c. Flush = plain coalesced stores.
__global__ __launch_bounds__(256) void hist_lds_kernel(
        const int* __restrict__ dst, const float* __restrict__ w,
        int* __restrict__ pc, float* __restrict__ pw,
        int NPAD, int NR, int EC, int E) {
    __shared__ int lc[RSIZE];
    __shared__ float lw[RSIZE];
    int r = blockIdx.x % NR;
    int c = blockIdx.x / NR;
    int t = threadIdx.x;
    for (int b = t; b < RSIZE; b += 256) { lc[b] = 0; lw[b] = 0.0f; }
    __syncthreads();
    int base = c * EC;
    int end = min(base + EC, E);
    int rbase = r << RBITS;
    for (int e = base + t; e < end; e += 256) {
        int d = dst[e];
        float wv = w[e];
        if ((d >> RBITS) == r) {
            atomicAdd(&lc[d - rbase], 1);
            atomicAdd(&lw[d - rbase], wv);
        }
    }
    __syncthreads();
    size_t o = (size_t)c * NPAD + rbase;
    for (int b = t; b < RSIZE; b += 256) {
        pc[o + b] = lc[b];
        pw[o + b] = lw[b];
    }
}

// counts[i] = sum_c pc[c][i];  dinv[i] = rsqrt(1 + sum_c pw[c][i])
__global__ __launch_bounds__(256) void reduce_hist_kernel(
        const int* __restrict__ pc, const float* __restrict__ pw,
        int* __restrict__ counts, float* __restrict__ dinv,
        int NPAD, int NEC, int N) {
    int i = blockIdx.x * 256 + threadIdx.x;
    if (i >= N) return;
    int ctot = 0;
    float d = 1.0f;   // self-loop
    for (int c = 0; c < NEC; ++c) {
        ctot += pc[(size_t)c * NPAD + i];
        d += pw[(size_t)c * NPAD + i];
    }
    counts[i] = ctot;
    dinv[i] = (d > 0.0f) ? rsqrtf(d) : 0.0f;
}

// ---- hierarchical scan: partial sums (1024 elems / 256-thr block) ----
__global__ __launch_bounds__(256) void scan_partial_kernel(
        const int* __restrict__ counts, int* __restrict__ bsums, int n) {
    __shared__ int ws[4];
    int b = blockIdx.x, t = threadIdx.x;
    int idx = b * 1024 + t * 4;
    int4 v = {0, 0, 0, 0};
    if (idx + 3 < n) v = *(const int4*)(counts + idx);
    else {
        if (idx < n) v.x = counts[idx];
        if (idx + 1 < n) v.y = counts[idx + 1];
        if (idx + 2 < n) v.z = counts[idx + 2];
        if (idx + 3 < n) v.w = counts[idx + 3];
    }
    int s = v.x + v.y + v.z + v.w;
    for (int off = 1; off < 64; off <<= 1) s += __shfl_xor(s, off, 64);
    if ((t & 63) == 0) ws[t >> 6] = s;
    __syncthreads();
    if (t == 0) bsums[b] = ws[0] + ws[1] + ws[2] + ws[3];
}

// scan of nb (<=1024) block sums -> exclusive; writes row_ptr[n]
__global__ __launch_bounds__(1024) void scan_bsums_kernel(
        int* __restrict__ bsums, int* __restrict__ rp_total, int nb) {
    __shared__ int ws[16];
    int t = threadIdx.x;
    int v = (t < nb) ? bsums[t] : 0;
    int lane = t & 63, wid = t >> 6;
    int x = v;
    for (int off = 1; off < 64; off <<= 1) {
        int y = __shfl_up(x, off, 64);
        if (lane >= off) x += y;
    }
    if (lane == 63) ws[wid] = x;
    __syncthreads();
    if (wid == 0) {
        int s = (lane < 16) ? ws[lane] : 0;
        for (int off = 1; off < 16; off <<= 1) {
            int y = __shfl_up(s, off, 64);
            if (lane >= off) s += y;
        }
        if (lane < 16) ws[lane] = s;
    }
    __syncthreads();
    int excl = x - v + ((wid == 0) ? 0 : ws[wid - 1]);
    if (t < nb) bsums[t] = excl;
    if (t == nb - 1) *rp_total = excl + v;
}

// final: per-block local scan + block offset -> row_ptr
__global__ __launch_bounds__(256) void scan_final_kernel(
        const int* __restrict__ counts, const int* __restrict__ bsums,
        int* __restrict__ row_ptr, int n) {
    __shared__ int ws[4];
    int b = blockIdx.x, t = threadIdx.x;
    int idx = b * 1024 + t * 4;
    int4 v = {0, 0, 0, 0};
    if (idx + 3 < n) v = *(const int4*)(counts + idx);
    else {
        if (idx < n) v.x = counts[idx];
        if (idx + 1 < n) v.y = counts[idx + 1];
        if (idx + 2 < n) v.z = counts[idx + 2];
        if (idx + 3 < n) v.w = counts[idx + 3];
    }
    int s = v.x + v.y + v.z + v.w;
    int lane = t & 63, wid = t >> 6;
    int x = s;
    for (int off = 1; off < 64; off <<= 1) {
        int y = __shfl_up(x, off, 64);
        if (lane >= off) x += y;
    }
    if (lane == 63) ws[wid] = x;
    __syncthreads();
    int woff = 0;
    for (int wv = 0; wv < wid; ++wv) woff += ws[wv];
    int run = bsums[b] + woff + x - s;
    int4 rp;
    rp.x = run; rp.y = run + v.x; rp.z = rp.y + v.y; rp.w = rp.z + v.z;
    if (idx + 3 < n) {
        *(int4*)(row_ptr + idx) = rp;
    } else {
        if (idx < n) row_ptr[idx] = rp.x;
        if (idx + 1 < n) row_ptr[idx + 1] = rp.y;
        if (idx + 2 < n) row_ptr[idx + 2] = rp.z;
        if (idx + 3 < n) row_ptr[idx + 3] = rp.w;
    }
}

// pc[c][d] (counts) -> per-chunk CSR base offsets (in place):
// pc[c][d] := row_ptr[d] + sum_{c'<c} cnt[c'][d]
__global__ __launch_bounds__(256) void col_scan_kernel(
        const int* __restrict__ row_ptr, int* __restrict__ pc,
        int NPAD, int NEC, int n) {
    int i = blockIdx.x * 256 + threadIdx.x;
    if (i >= n) return;
    int run = row_ptr[i];
    for (int c = 0; c < NEC; ++c) {
        size_t idx = (size_t)c * NPAD + i;
        int v = pc[idx];
        pc[idx] = run;
        run += v;
    }
}

// fill via packed-ushort LDS ranks (no global atomics). Block c = edge chunk.
__global__ __launch_bounds__(1024) void fill2_kernel(
        const int* __restrict__ src, const int* __restrict__ dst,
        const float* __restrict__ w, const float* __restrict__ dinv,
        const int* __restrict__ pc, int* __restrict__ src_s,
        float* __restrict__ norm_s, int NPAD, int EC, int E) {
    __shared__ unsigned pk[MAXN_HALF];
    int c = blockIdx.x, t = threadIdx.x;
    for (int b = t; b < MAXN_HALF; b += 1024) pk[b] = 0u;
    __syncthreads();
    int base = c * EC;
    int end = min(base + EC, E);
    const int* __restrict__ pco = pc + (size_t)c * NPAD;
    for (int e = base + t; e < end; e += 1024) {
        int d = dst[e];
        int s = src[e];
        float wv = w[e];
        unsigned sh = (d & 1) * 16;
        unsigned old = atomicAdd(&pk[d >> 1], 1u << sh);
        int rank = (old >> sh) & 0xFFFF;
        int pos = pco[d] + rank;
        src_s[pos] = s;
        norm_s[pos] = dinv[s] * wv * dinv[d];
    }
}

// Fused-weight build, parallel+coalesced. grid (3,16), 256 thr.
__global__ __launch_bounds__(256) void fuse_weights_kernel(
        const float* __restrict__ Wz, const float* __restrict__ Wr,
        const float* __restrict__ Wh,
        const float* __restrict__ lzW, const float* __restrict__ lrW,
        const float* __restrict__ lhW,
        ushort* __restrict__ BT) {
    int g = blockIdx.x, kt = blockIdx.y;
    const float* W  = (g == 0) ? Wz  : (g == 1) ? Wr  : Wh;
    const float* lW = (g == 0) ? lzW : (g == 1) ? lrW : lhW;
    int t = threadIdx.x;
    int j = t & 127, kh = t >> 7;          // kh in {0,1}
    int k0 = kt * 8 + kh * 4;
    float m0 = 0.f, m1 = 0.f, m2 = 0.f, m3 = 0.f;
    for (int mm = 0; mm < 128; ++mm) {
        float lv = lW[mm * 128 + j];       // coalesced across j
        m0 += W[(k0 + 0) * 128 + mm] * lv; // wave-uniform -> broadcast
        m1 += W[(k0 + 1) * 128 + mm] * lv;
        m2 += W[(k0 + 2) * 128 + mm] * lv;
        m3 += W[(k0 + 3) * 128 + mm] * lv;
    }
    ushort* dstc = BT + ((size_t)g * 128 + j) * 256;
    dstc[k0 + 0] = f2bf(m0); dstc[k0 + 1] = f2bf(m1);
    dstc[k0 + 2] = f2bf(m2); dstc[k0 + 3] = f2bf(m3);
#pragma unroll
    for (int u = 0; u < 4; ++u) {
        int mm = k0 + u;
        dstc[128 + mm] = f2bf(lW[(128 + mm) * 128 + j]);
    }
}

// lb2[g][j] = lgb[j] + sum_m bg[m]*lgW_top[m][j]
__global__ __launch_bounds__(128) void lb2_kernel(
        const float* __restrict__ lzW, const float* __restrict__ lrW,
        const float* __restrict__ lhW,
        const float* __restrict__ bz, const float* __restrict__ br,
        const float* __restrict__ bh,
        const float* __restrict__ lzb, const float* __restrict__ lrb,
        const float* __restrict__ lhb,
        float* __restrict__ lb2) {
    int g = blockIdx.x, j = threadIdx.x;
    const float* lW = (g == 0) ? lzW : (g == 1) ? lrW : lhW;
    const float* bg = (g == 0) ? bz  : (g == 1) ? br  : bh;
    const float* lb = (g == 0) ? lzb : (g == 1) ? lrb : lhb;
    float s = lb[j];
    for (int mm = 0; mm < 128; ++mm) s += bg[mm] * lW[mm * 128 + j];
    lb2[g * 128 + j] = s;
}

// aggb[i,:] = bf16( dinv[i]^2 * nfb[i,:] + sum_e norm[e] * nfb[src[e],:] )
__global__ __launch_bounds__(256) void agg_feat_kernel(
        const unsigned* __restrict__ nfb32, const float* __restrict__ dinv,
        const int* __restrict__ row_ptr, const int* __restrict__ src_s,
        const float* __restrict__ norm_s, unsigned* __restrict__ aggb32, int n) {
    int t = threadIdx.x & 63;            // column pair
    int grp = threadIdx.x >> 6;
    int i = blockIdx.x * 4 + grp;
    if (i >= n) return;
    float di = dinv[i];
    unsigned uself = nfb32[(size_t)i * 64 + t];
    float a0 = di * di * bflo(uself);
    float a1 = di * di * bfhi(uself);
    int e0 = row_ptr[i], e1 = row_ptr[i + 1];
    for (int e = e0; e < e1; e += 8) {
        unsigned v[8]; float w[8];
#pragma unroll
        for (int u = 0; u < 8; ++u) {
            int ee = e + u;
            bool ok = ee < e1;
            int s = ok ? src_s[ee] : src_s[e0];
            w[u] = ok ? norm_s[ee] : 0.0f;
            v[u] = nfb32[(size_t)s * 64 + t];
        }
#pragma unroll
        for (int u = 0; u < 8; ++u) {
            a0 += w[u] * bflo(v[u]);
            a1 += w[u] * bfhi(v[u]);
        }
    }
    aggb32[(size_t)i * 64 + t] = (unsigned)f2bf(a0) | ((unsigned)f2bf(a1) << 16);
}

// Fused GRU: 64-row tile per block, 4 waves; wave w owns a 32-col slice and
// ALL 64 rows. Per phase: 16 independent B-loads into REGISTERS (one latency
// round), then 32 LDS A-reads + 64 MFMAs. hq goes to a 3rd LDS buffer.
__global__ __launch_bounds__(256) void gru_fused_kernel(
        const ushort* __restrict__ aggb, const ushort* __restrict__ h0b,
        const ushort* __restrict__ BT, const float* __restrict__ lb2,
        float* __restrict__ hout, int n) {
    __shared__ ushort Aag[64][136];   // agg tile (pad 8 -> 2-way alias, free)
    __shared__ ushort Ah0[64][136];   // h0 tile (bf16)
    __shared__ ushort Ahq[64][136];   // h0*r tile
    int t = threadIdx.x;
    int i0 = blockIdx.x * 64;

    for (int c = t; c < 1024; c += 256) {
        int row = c >> 4, c8 = c & 15;
        size_t gp = (size_t)(i0 + row) * HD + c8 * 8;
        *(short8*)&Aag[row][c8 * 8] = *(const short8*)(aggb + gp);
        *(short8*)&Ah0[row][c8 * 8] = *(const short8*)(h0b + gp);
    }
    __syncthreads();

    int w = t >> 6, lane = t & 63;
    int rlo = lane & 15, koff = (lane >> 4) * 8, rbase = (lane >> 4) * 4;
    int c0 = w * 32;                    // wave's column base within gate

    const f32x4 zero4 = {0.f, 0.f, 0.f, 0.f};
    short8 bfr[2][8];
    f32x4 acc[4][2];
    float zv[4][2][4];

    // ================= phase Z (gate 0) =================
#pragma unroll
    for (int cf = 0; cf < 2; ++cf)
#pragma unroll
        for (int ks = 0; ks < 8; ++ks)
            bfr[cf][ks] = *(const short8*)(BT + (size_t)(c0 + cf * 16 + rlo) * 256
                                           + ks * 32 + koff);
#pragma unroll
    for (int rf = 0; rf < 4; ++rf) { acc[rf][0] = zero4; acc[rf][1] = zero4; }
#pragma unroll
    for (int rf = 0; rf < 4; ++rf)
#pragma unroll
        for (int ks = 0; ks < 8; ++ks) {
            short8 af = (ks < 4)
                ? *(const short8*)&Aag[rf * 16 + rlo][ks * 32 + koff]
                : *(const short8*)&Ah0[rf * 16 + rlo][(ks - 4) * 32 + koff];
            acc[rf][0] = __builtin_amdgcn_mfma_f32_16x16x32_bf16(af, bfr[0][ks], acc[rf][0], 0, 0, 0);
            acc[rf][1] = __builtin_amdgcn_mfma_f32_16x16x32_bf16(af, bfr[1][ks], acc[rf][1], 0, 0, 0);
        }
#pragma unroll
    for (int rf = 0; rf < 4; ++rf)
#pragma unroll
        for (int cf = 0; cf < 2; ++cf) {
            float bv = lb2[c0 + cf * 16 + rlo];
#pragma unroll
            for (int i = 0; i < 4; ++i)
                zv[rf][cf][i] = fast_sigmoid(acc[rf][cf][i] + bv);
        }

    // ================= phase R (gate 1) =================
#pragma unroll
    for (int cf = 0; cf < 2; ++cf)
#pragma unroll
        for (int ks = 0; ks < 8; ++ks)
            bfr[cf][ks] = *(const short8*)(BT + (size_t)(128 + c0 + cf * 16 + rlo) * 256
                                           + ks * 32 + koff);
#pragma unroll
    for (int rf = 0; rf < 4; ++rf) { acc[rf][0] = zero4; acc[rf][1] = zero4; }
#pragma unroll
    for (int rf = 0; rf < 4; ++rf)
#pragma unroll
        for (int ks = 0; ks < 8; ++ks) {
            short8 af = (ks < 4)
                ? *(const short8*)&Aag[rf * 16 + rlo][ks * 32 + koff]
                : *(const short8*)&Ah0[rf * 16 + rlo][(ks - 4) * 32 + koff];
            acc[rf][0] = __builtin_amdgcn_mfma_f32_16x16x32_bf16(af, bfr[0][ks], acc[rf][0], 0, 0, 0);
            acc[rf][1] = __builtin_amdgcn_mfma_f32_16x16x32_bf16(af, bfr[1][ks], acc[rf][1], 0, 0, 0);
        }
#pragma unroll
    for (int rf = 0; rf < 4; ++rf)
#pragma unroll
        for (int cf = 0; cf < 2; ++cf) {
            int lc = c0 + cf * 16 + rlo;
            float bv = lb2[128 + lc];
#pragma unroll
            for (int i = 0; i < 4; ++i) {
                int row = rf * 16 + rbase + i;
                float r = fast_sigmoid(acc[rf][cf][i] + bv);
                Ahq[row][lc] = f2bf(r * bf2f(Ah0[row][lc]));
            }
        }
    __syncthreads();   // hq visible to all waves

    // ================= phase HT (gate 2): A = [agg | hq] =================
#pragma unroll
    for (int cf = 0; cf < 2; ++cf)
#pragma unroll
        for (int ks = 0; ks < 8; ++ks)
            bfr[cf][ks] = *(const short8*)(BT + (size_t)(256 + c0 + cf * 16 + rlo) * 256
                                           + ks * 32 + koff);
#pragma unroll
    for (int rf = 0; rf < 4; ++rf) { acc[rf][0] = zero4; acc[rf][1] = zero4; }
#pragma unroll
    for (int rf = 0; rf < 4; ++rf)
#pragma unroll
        for (int ks = 0; ks < 8; ++ks) {
            short8 af = (ks < 4)
                ? *(const short8*)&Aag[rf * 16 + rlo][ks * 32 + koff]
                : *(const short8*)&Ahq[rf * 16 + rlo][(ks - 4) * 32 + koff];
            acc[rf][0] = __builtin_amdgcn_mfma_f32_16x16x32_bf16(af, bfr[0][ks], acc[rf][0], 0, 0, 0);
            acc[rf][1] = __builtin_amdgcn_mfma_f32_16x16x32_bf16(af, bfr[1][ks], acc[rf][1], 0, 0, 0);
        }
#pragma unroll
    for (int rf = 0; rf < 4; ++rf)
#pragma unroll
        for (int cf = 0; cf < 2; ++cf) {
            int lc = c0 + cf * 16 + rlo;
            float bv = lb2[256 + lc];
#pragma unroll
            for (int i = 0; i < 4; ++i) {
                int row = rf * 16 + rbase + i;
                int grow = i0 + row;
                if (grow < n) {
                    float ht = fast_tanh(acc[rf][cf][i] + bv);
                    float z = zv[rf][cf][i];
                    float h0v = bf2f(Ah0[row][lc]);
                    hout[(size_t)grow * HD + lc] = z * h0v + (1.0f - z) * ht;
                }
            }
        }
}

__global__ __launch_bounds__(128) void pool_kernel(
        const float* __restrict__ hout, const int* __restrict__ nids,
        float* pooled, int U) {
    int t = threadIdx.x;
    float pa = 0.0f;
    for (int u = blockIdx.x; u < U; u += gridDim.x) {
        int nid = nids[u];
        pa += fmaxf(hout[(size_t)nid * HD + t], 0.0f);
    }
    atomicAdd(&pooled[t], pa);
}

__global__ __launch_bounds__(128) void decoder_kernel(
        const float* __restrict__ pooled, float invU,
        const float* __restrict__ linW, const float* __restrict__ linb,
        const float* __restrict__ dnW, const float* __restrict__ dnb,
        const float* __restrict__ outW, const float* __restrict__ outb,
        float* pred, int C) {
    __shared__ float sh[HD];
    int t = threadIdx.x;
    sh[t] = pooled[t] * invU;
    __syncthreads();
    float v = linb[t];
    for (int k = 0; k < HD; ++k) v += sh[k] * linW[k * HD + t];
    __syncthreads();
    sh[t] = v;
    __syncthreads();
    float d = dnb[t];
    for (int k = 0; k < HD; ++k) d += sh[k] * dnW[k * HD + t];
    d = fmaxf(d, 0.0f);
    __syncthreads();
    sh[t] = d;
    __syncthreads();
    if (t < C) {
        float p = outb[t];
        for (int k = 0; k < HD; ++k) p += sh[k] * outW[k * C + t];
        pred[t] = 1.0f / (1.0f + expf(-p));
    }
}

extern "C" void kernel_launch(void* const* d_in, const int* in_sizes, int n_in,
                              void* d_out, int out_size, void* d_ws, size_t ws_size,
                              hipStream_t stream) {
    const float* node_feat = (const float*)d_in[0];
    const float* edge_w    = (const float*)d_in[1];
    const float* h0        = (const float*)d_in[2];
    const float* Wz  = (const float*)d_in[3];  const float* bz  = (const float*)d_in[4];
    const float* Wr  = (const float*)d_in[5];  const float* br  = (const float*)d_in[6];
    const float* Wh  = (const float*)d_in[7];  const float* bh  = (const float*)d_in[8];
    const float* lzW = (const float*)d_in[9];  const float* lzb = (const float*)d_in[10];
    const float* lrW = (const float*)d_in[11]; const float* lrb = (const float*)d_in[12];
    const float* lhW = (const float*)d_in[13]; const float* lhb = (const float*)d_in[14];
    const float* linW= (const float*)d_in[15]; const float* linb= (const float*)d_in[16];
    const float* dnW = (const float*)d_in[17]; const float* dnb = (const float*)d_in[18];
    const float* outW= (const float*)d_in[19]; const float* outb= (const float*)d_in[20];
    const int* src  = (const int*)d_in[21];
    const int* dst  = (const int*)d_in[22];
    const int* nids = (const int*)d_in[23];

    const int N = in_sizes[2] / HD;
    const int E = in_sizes[1];
    const int U = in_sizes[23];
    const int C = in_sizes[20];
    const int NP = (N + 127) & ~127;    // row-padded
    const int NB1K = (N + 1023) / 1024; // scan blocks
    const int NR = (N + RSIZE - 1) / RSIZE;       // histogram ranges
    const int NPAD = NR * RSIZE;
    int NEC = 64;                                  // edge chunks
    {   // keep per-chunk counts < 65536 for packed ushort ranks
        int minc = (E + 65535) / 65536;
        if (NEC < minc) NEC = minc;
    }
    const int EC = (E + NEC - 1) / NEC;

    float* out  = (float*)d_out;
    float* pred = out;          // [C]
    float* hout = out + C;      // [N,H]

    // workspace layout (16B-aligned chunks)
    char* p = (char*)d_ws;
    auto alloc = [&](size_t bytes) { char* r = p; p += (bytes + 15) & ~(size_t)15; return r; };
    float* dinv   = (float*)alloc((size_t)N * 4);
    float* norm_s = (float*)alloc((size_t)E * 4);
    float* pooled = (float*)alloc(HD * 4);
    int*   counts = (int*)alloc((size_t)N * 4);
    int*   row_ptr= (int*)alloc((size_t)(N + 1) * 4);
    int*   src_s  = (int*)alloc((size_t)E * 4);
    int*   bsums  = (int*)alloc((size_t)1024 * 4);
    int*   pc     = (int*)alloc((size_t)NEC * NPAD * 4);
    float* pw     = (float*)alloc((size_t)NEC * NPAD * 4);
    ushort* nfb   = (ushort*)alloc((size_t)NP * HD * 2);
    ushort* aggb  = (ushort*)alloc((size_t)NP * HD * 2);
    ushort* h0b   = (ushort*)alloc((size_t)NP * HD * 2);
    ushort* BT    = (ushort*)alloc((size_t)3 * 128 * 256 * 2);
    float* lb2    = (float*)alloc(384 * 4);

    hipMemsetAsync(pooled, 0, HD * sizeof(float), stream);

    int prep_items = N * (HD / 8);
    prep_kernel<<<(prep_items + 255) / 256, 256, 0, stream>>>(node_feat, h0, nfb, h0b, N);
    hist_lds_kernel<<<NR * NEC, 256, 0, stream>>>(dst, edge_w, pc, pw, NPAD, NR, EC, E);
    reduce_hist_kernel<<<(N + 255) / 256, 256, 0, stream>>>(pc, pw, counts, dinv,
                                                            NPAD, NEC, N);
    scan_partial_kernel<<<NB1K, 256, 0, stream>>>(counts, bsums, N);
    scan_bsums_kernel<<<1, 1024, 0, stream>>>(bsums, row_ptr + N, NB1K);
    scan_final_kernel<<<NB1K, 256, 0, stream>>>(counts, bsums, row_ptr, N);
    col_scan_kernel<<<(N + 255) / 256, 256, 0, stream>>>(row_ptr, pc, NPAD, NEC, N);
    fill2_kernel<<<NEC, 1024, 0, stream>>>(src, dst, edge_w, dinv, pc,
                                           src_s, norm_s, NPAD, EC, E);
    dim3 fg(3, 16);
    fuse_weights_kernel<<<fg, 256, 0, stream>>>(Wz, Wr, Wh, lzW, lrW, lhW, BT);
    lb2_kernel<<<3, 128, 0, stream>>>(lzW, lrW, lhW, bz, br, bh, lzb, lrb, lhb, lb2);
    agg_feat_kernel<<<(N + 3) / 4, 256, 0, stream>>>(
        (const unsigned*)nfb, dinv, row_ptr, src_s, norm_s, (unsigned*)aggb, N);
    gru_fused_kernel<<<NP / 64, 256, 0, stream>>>(aggb, h0b, BT, lb2, hout, N);
    pool_kernel<<<512, 128, 0, stream>>>(hout, nids, pooled, U);
    decoder_kernel<<<1, 128, 0, stream>>>(pooled, 1.0f / (float)U,
                                          linW, linb, dnW, dnb, outW, outb, pred, C);
}

// Round 11
// 304.176 us; speedup vs baseline: 1.0891x; 1.0891x over previous
//
#include <hip/hip_runtime.h>
#include <math.h>

// TGCN: bf16 feature-space GCN aggregation (fp32 accum) -> single fused GRU
// kernel (z,r,hq,ht in one pass; B-slice in REGISTERS per wave, A in LDS).
// CSR-by-dst built with ZERO global atomics. CSR payload is an interleaved
// int2 {src, norm} so each edge costs ONE scattered 8B store, and the fill
// runs on a (chunk x range) grid with 16KB LDS rank cursors.

#define HD 128
#define RBITS 13
#define RSIZE 8192          // nodes per histogram/fill range

typedef __attribute__((ext_vector_type(8))) short short8;
typedef __attribute__((ext_vector_type(4))) float f32x4;

__device__ __forceinline__ ushort f2bf(float f) {
    union { float f; unsigned u; } v; v.f = f;
    unsigned r = (v.u + 0x7FFFu + ((v.u >> 16) & 1u)) >> 16;
    return (ushort)r;
}
__device__ __forceinline__ float bf2f(ushort h) {
    union { unsigned u; float f; } v; v.u = ((unsigned)h) << 16;
    return v.f;
}
__device__ __forceinline__ float bflo(unsigned u) {
    union { unsigned u; float f; } v; v.u = u << 16; return v.f;
}
__device__ __forceinline__ float bfhi(unsigned u) {
    union { unsigned u; float f; } v; v.u = u & 0xFFFF0000u; return v.f;
}
__device__ __forceinline__ float fast_sigmoid(float x) {
    return 1.0f / (1.0f + __expf(-x));
}
__device__ __forceinline__ float fast_tanh(float x) {
    float e = __expf(-2.0f * fabsf(x));
    float m = (1.0f - e) / (1.0f + e);
    return copysignf(m, x);
}

// nf -> bf16, h0 -> bf16 (vectorized)
__global__ void prep_kernel(const float* __restrict__ nf, const float* __restrict__ h0,
                            ushort* __restrict__ nfb, ushort* __restrict__ h0b, int n) {
    int idx = blockIdx.x * 256 + threadIdx.x;
    int total8 = n * (HD / 8);
    if (idx < total8) {
        const float4* p = (const float4*)(nf + (size_t)idx * 8);
        float4 x = p[0], y = p[1];
        short8 o;
        o[0] = (short)f2bf(x.x); o[1] = (short)f2bf(x.y);
        o[2] = (short)f2bf(x.z); o[3] = (short)f2bf(x.w);
        o[4] = (short)f2bf(y.x); o[5] = (short)f2bf(y.y);
        o[6] = (short)f2bf(y.z); o[7] = (short)f2bf(y.w);
        *(short8*)(nfb + (size_t)idx * 8) = o;
        const float4* q = (const float4*)(h0 + (size_t)idx * 8);
        float4 a = q[0], b = q[1];
        short8 o2;
        o2[0] = (short)f2bf(a.x); o2[1] = (short)f2bf(a.y);
        o2[2] = (short)f2bf(a.z); o2[3] = (short)f2bf(a.w);
        o2[4] = (short)f2bf(b.x); o2[5] = (short)f2bf(b.y);
        o2[6] = (short)f2bf(b.z); o2[7] = (short)f2bf(b.w);
        *(short8*)(h0b + (size_t)idx * 8) = o2;
    }
}

// LDS-privatized histogram. Block (r = bid%NR, c = bid/NR): counts/weights of
// dst in range r over edge chunk c. Flush = plain coalesced stores.
__global__ __launch_bounds__(256) void hist_lds_kernel(
        const int* __restrict__ dst, const float* __restrict__ w,
        int* __restrict__ pc, float* __restrict__ pw,
        int NPAD, int NR, int EC, int E) {
    __shared__ int lc[RSIZE];
    __shared__ float lw[RSIZE];
    int r = blockIdx.x % NR;
    int c = blockIdx.x / NR;
    int t = threadIdx.x;
    for (int b = t; b < RSIZE; b += 256) { lc[b] = 0; lw[b] = 0.0f; }
    __syncthreads();
    int base = c * EC;
    int end = min(base + EC, E);
    int rbase = r << RBITS;
    for (int e = base + t; e < end; e += 256) {
        int d = dst[e];
        float wv = w[e];
        if ((d >> RBITS) == r) {
            atomicAdd(&lc[d - rbase], 1);
            atomicAdd(&lw[d - rbase], wv);
        }
    }
    __syncthreads();
    size_t o = (size_t)c * NPAD + rbase;
    for (int b = t; b < RSIZE; b += 256) {
        pc[o + b] = lc[b];
        pw[o + b] = lw[b];
    }
}

// counts[i] = sum_c pc[c][i];  dinv[i] = rsqrt(1 + sum_c pw[c][i])
__global__ __launch_bounds__(256) void reduce_hist_kernel(
        const int* __restrict__ pc, const float* __restrict__ pw,
        int* __restrict__ counts, float* __restrict__ dinv,
        int NPAD, int NEC, int N) {
    int i = blockIdx.x * 256 + threadIdx.x;
    if (i >= N) return;
    int ctot = 0;
    float d = 1.0f;   // self-loop
    for (int c = 0; c < NEC; ++c) {
        ctot += pc[(size_t)c * NPAD + i];
        d += pw[(size_t)c * NPAD + i];
    }
    counts[i] = ctot;
    dinv[i] = (d > 0.0f) ? rsqrtf(d) : 0.0f;
}

// ---- hierarchical scan: partial sums (1024 elems / 256-thr block) ----
__global__ __launch_bounds__(256) void scan_partial_kernel(
        const int* __restrict__ counts, int* __restrict__ bsums, int n) {
    __shared__ int ws[4];
    int b = blockIdx.x, t = threadIdx.x;
    int idx = b * 1024 + t * 4;
    int4 v = {0, 0, 0, 0};
    if (idx + 3 < n) v = *(const int4*)(counts + idx);
    else {
        if (idx < n) v.x = counts[idx];
        if (idx + 1 < n) v.y = counts[idx + 1];
        if (idx + 2 < n) v.z = counts[idx + 2];
        if (idx + 3 < n) v.w = counts[idx + 3];
    }
    int s = v.x + v.y + v.z + v.w;
    for (int off = 1; off < 64; off <<= 1) s += __shfl_xor(s, off, 64);
    if ((t & 63) == 0) ws[t >> 6] = s;
    __syncthreads();
    if (t == 0) bsums[b] = ws[0] + ws[1] + ws[2] + ws[3];
}

// scan of nb (<=1024) block sums -> exclusive; writes row_ptr[n]
__global__ __launch_bounds__(1024) void scan_bsums_kernel(
        int* __restrict__ bsums, int* __restrict__ rp_total, int nb) {
    __shared__ int ws[16];
    int t = threadIdx.x;
    int v = (t < nb) ? bsums[t] : 0;
    int lane = t & 63, wid = t >> 6;
    int x = v;
    for (int off = 1; off < 64; off <<= 1) {
        int y = __shfl_up(x, off, 64);
        if (lane >= off) x += y;
    }
    if (lane == 63) ws[wid] = x;
    __syncthreads();
    if (wid == 0) {
        int s = (lane < 16) ? ws[lane] : 0;
        for (int off = 1; off < 16; off <<= 1) {
            int y = __shfl_up(s, off, 64);
            if (lane >= off) s += y;
        }
        if (lane < 16) ws[lane] = s;
    }
    __syncthreads();
    int excl = x - v + ((wid == 0) ? 0 : ws[wid - 1]);
    if (t < nb) bsums[t] = excl;
    if (t == nb - 1) *rp_total = excl + v;
}

// final: per-block local scan + block offset -> row_ptr
__global__ __launch_bounds__(256) void scan_final_kernel(
        const int* __restrict__ counts, const int* __restrict__ bsums,
        int* __restrict__ row_ptr, int n) {
    __shared__ int ws[4];
    int b = blockIdx.x, t = threadIdx.x;
    int idx = b * 1024 + t * 4;
    int4 v = {0, 0, 0, 0};
    if (idx + 3 < n) v = *(const int4*)(counts + idx);
    else {
        if (idx < n) v.x = counts[idx];
        if (idx + 1 < n) v.y = counts[idx + 1];
        if (idx + 2 < n) v.z = counts[idx + 2];
        if (idx + 3 < n) v.w = counts[idx + 3];
    }
    int s = v.x + v.y + v.z + v.w;
    int lane = t & 63, wid = t >> 6;
    int x = s;
    for (int off = 1; off < 64; off <<= 1) {
        int y = __shfl_up(x, off, 64);
        if (lane >= off) x += y;
    }
    if (lane == 63) ws[wid] = x;
    __syncthreads();
    int woff = 0;
    for (int wv = 0; wv < wid; ++wv) woff += ws[wv];
    int run = bsums[b] + woff + x - s;
    int4 rp;
    rp.x = run; rp.y = run + v.x; rp.z = rp.y + v.y; rp.w = rp.z + v.z;
    if (idx + 3 < n) {
        *(int4*)(row_ptr + idx) = rp;
    } else {
        if (idx < n) row_ptr[idx] = rp.x;
        if (idx + 1 < n) row_ptr[idx + 1] = rp.y;
        if (idx + 2 < n) row_ptr[idx + 2] = rp.z;
        if (idx + 3 < n) row_ptr[idx + 3] = rp.w;
    }
}

// pc[c][d] (counts) -> per-chunk CSR base offsets (in place):
// pc[c][d] := row_ptr[d] + sum_{c'<c} cnt[c'][d]
__global__ __launch_bounds__(256) void col_scan_kernel(
        const int* __restrict__ row_ptr, int* __restrict__ pc,
        int NPAD, int NEC, int n) {
    int i = blockIdx.x * 256 + threadIdx.x;
    if (i >= n) return;
    int run = row_ptr[i];
    for (int c = 0; c < NEC; ++c) {
        size_t idx = (size_t)c * NPAD + i;
        int v = pc[idx];
        pc[idx] = run;
        run += v;
    }
}

// fill: block (c,r) assigns slots for chunk c's edges in range r via packed
// ushort LDS ranks; ONE interleaved int2 {src, norm} store per edge.
__global__ __launch_bounds__(256) void fill2d_kernel(
        const int* __restrict__ src, const int* __restrict__ dst,
        const float* __restrict__ w, const float* __restrict__ dinv,
        const int* __restrict__ pc, int2* __restrict__ es,
        int NPAD, int NR, int EC, int E) {
    __shared__ unsigned pk[RSIZE / 2];   // 16KB packed ushort cursors
    int r = blockIdx.x % NR;
    int c = blockIdx.x / NR;
    int t = threadIdx.x;
    for (int b = t; b < RSIZE / 2; b += 256) pk[b] = 0u;
    __syncthreads();
    int base = c * EC;
    int end = min(base + EC, E);
    int rbase = r << RBITS;
    const int* __restrict__ pco = pc + (size_t)c * NPAD;
    for (int e = base + t; e < end; e += 256) {
        int d = dst[e];
        if ((d >> RBITS) == r) {
            int dl = d - rbase;
            unsigned sh = (dl & 1) * 16;
            unsigned old = atomicAdd(&pk[dl >> 1], 1u << sh);
            int rank = (int)((old >> sh) & 0xFFFFu);
            int pos = pco[d] + rank;
            int s = src[e];
            float nv = dinv[s] * w[e] * dinv[d];
            int2 ev;
            ev.x = s;
            ev.y = __float_as_int(nv);
            es[pos] = ev;
        }
    }
}

// Fused-weight build, parallel+coalesced. grid (3,16), 256 thr.
__global__ __launch_bounds__(256) void fuse_weights_kernel(
        const float* __restrict__ Wz, const float* __restrict__ Wr,
        const float* __restrict__ Wh,
        const float* __restrict__ lzW, const float* __restrict__ lrW,
        const float* __restrict__ lhW,
        ushort* __restrict__ BT) {
    int g = blockIdx.x, kt = blockIdx.y;
    const float* W  = (g == 0) ? Wz  : (g == 1) ? Wr  : Wh;
    const float* lW = (g == 0) ? lzW : (g == 1) ? lrW : lhW;
    int t = threadIdx.x;
    int j = t & 127, kh = t >> 7;          // kh in {0,1}
    int k0 = kt * 8 + kh * 4;
    float m0 = 0.f, m1 = 0.f, m2 = 0.f, m3 = 0.f;
    for (int mm = 0; mm < 128; ++mm) {
        float lv = lW[mm * 128 + j];       // coalesced across j
        m0 += W[(k0 + 0) * 128 + mm] * lv; // wave-uniform -> broadcast
        m1 += W[(k0 + 1) * 128 + mm] * lv;
        m2 += W[(k0 + 2) * 128 + mm] * lv;
        m3 += W[(k0 + 3) * 128 + mm] * lv;
    }
    ushort* dstc = BT + ((size_t)g * 128 + j) * 256;
    dstc[k0 + 0] = f2bf(m0); dstc[k0 + 1] = f2bf(m1);
    dstc[k0 + 2] = f2bf(m2); dstc[k0 + 3] = f2bf(m3);
#pragma unroll
    for (int u = 0; u < 4; ++u) {
        int mm = k0 + u;
        dstc[128 + mm] = f2bf(lW[(128 + mm) * 128 + j]);
    }
}

// lb2[g][j] = lgb[j] + sum_m bg[m]*lgW_top[m][j]
__global__ __launch_bounds__(128) void lb2_kernel(
        const float* __restrict__ lzW, const float* __restrict__ lrW,
        const float* __restrict__ lhW,
        const float* __restrict__ bz, const float* __restrict__ br,
        const float* __restrict__ bh,
        const float* __restrict__ lzb, const float* __restrict__ lrb,
        const float* __restrict__ lhb,
        float* __restrict__ lb2) {
    int g = blockIdx.x, j = threadIdx.x;
    const float* lW = (g == 0) ? lzW : (g == 1) ? lrW : lhW;
    const float* bg = (g == 0) ? bz  : (g == 1) ? br  : bh;
    const float* lb = (g == 0) ? lzb : (g == 1) ? lrb : lhb;
    float s = lb[j];
    for (int mm = 0; mm < 128; ++mm) s += bg[mm] * lW[mm * 128 + j];
    lb2[g * 128 + j] = s;
}

// aggb[i,:] = bf16( dinv[i]^2 * nfb[i,:] + sum_e norm[e] * nfb[src[e],:] )
__global__ __launch_bounds__(256) void agg_feat_kernel(
        const unsigned* __restrict__ nfb32, const float* __restrict__ dinv,
        const int* __restrict__ row_ptr, const int2* __restrict__ es,
        unsigned* __restrict__ aggb32, int n) {
    int t = threadIdx.x & 63;            // column pair
    int grp = threadIdx.x >> 6;
    int i = blockIdx.x * 4 + grp;
    if (i >= n) return;
    float di = dinv[i];
    unsigned uself = nfb32[(size_t)i * 64 + t];
    float a0 = di * di * bflo(uself);
    float a1 = di * di * bfhi(uself);
    int e0 = row_ptr[i], e1 = row_ptr[i + 1];
    for (int e = e0; e < e1; e += 8) {
        unsigned v[8]; float w[8];
#pragma unroll
        for (int u = 0; u < 8; ++u) {
            int ee = e + u;
            bool ok = ee < e1;
            int2 ev = ok ? es[ee] : es[e0];
            w[u] = ok ? __int_as_float(ev.y) : 0.0f;
            v[u] = nfb32[(size_t)ev.x * 64 + t];
        }
#pragma unroll
        for (int u = 0; u < 8; ++u) {
            a0 += w[u] * bflo(v[u]);
            a1 += w[u] * bfhi(v[u]);
        }
    }
    aggb32[(size_t)i * 64 + t] = (unsigned)f2bf(a0) | ((unsigned)f2bf(a1) << 16);
}

// Fused GRU: 64-row tile per block, 4 waves; wave w owns a 32-col slice and
// ALL 64 rows. Per phase: 16 independent B-loads into REGISTERS (one latency
// round), then 32 LDS A-reads + 64 MFMAs. hq goes to a 3rd LDS buffer.
__global__ __launch_bounds__(256) void gru_fused_kernel(
        const ushort* __restrict__ aggb, const ushort* __restrict__ h0b,
        const ushort* __restrict__ BT, const float* __restrict__ lb2,
        float* __restrict__ hout, int n) {
    __shared__ ushort Aag[64][136];   // agg tile (pad 8 -> 2-way alias, free)
    __shared__ ushort Ah0[64][136];   // h0 tile (bf16)
    __shared__ ushort Ahq[64][136];   // h0*r tile
    int t = threadIdx.x;
    int i0 = blockIdx.x * 64;

    for (int c = t; c < 1024; c += 256) {
        int row = c >> 4, c8 = c & 15;
        size_t gp = (size_t)(i0 + row) * HD + c8 * 8;
        *(short8*)&Aag[row][c8 * 8] = *(const short8*)(aggb + gp);
        *(short8*)&Ah0[row][c8 * 8] = *(const short8*)(h0b + gp);
    }
    __syncthreads();

    int w = t >> 6, lane = t & 63;
    int rlo = lane & 15, koff = (lane >> 4) * 8, rbase = (lane >> 4) * 4;
    int c0 = w * 32;                    // wave's column base within gate

    const f32x4 zero4 = {0.f, 0.f, 0.f, 0.f};
    short8 bfr[2][8];
    f32x4 acc[4][2];
    float zv[4][2][4];

    // ================= phase Z (gate 0) =================
#pragma unroll
    for (int cf = 0; cf < 2; ++cf)
#pragma unroll
        for (int ks = 0; ks < 8; ++ks)
            bfr[cf][ks] = *(const short8*)(BT + (size_t)(c0 + cf * 16 + rlo) * 256
                                           + ks * 32 + koff);
#pragma unroll
    for (int rf = 0; rf < 4; ++rf) { acc[rf][0] = zero4; acc[rf][1] = zero4; }
#pragma unroll
    for (int rf = 0; rf < 4; ++rf)
#pragma unroll
        for (int ks = 0; ks < 8; ++ks) {
            short8 af = (ks < 4)
                ? *(const short8*)&Aag[rf * 16 + rlo][ks * 32 + koff]
                : *(const short8*)&Ah0[rf * 16 + rlo][(ks - 4) * 32 + koff];
            acc[rf][0] = __builtin_amdgcn_mfma_f32_16x16x32_bf16(af, bfr[0][ks], acc[rf][0], 0, 0, 0);
            acc[rf][1] = __builtin_amdgcn_mfma_f32_16x16x32_bf16(af, bfr[1][ks], acc[rf][1], 0, 0, 0);
        }
#pragma unroll
    for (int rf = 0; rf < 4; ++rf)
#pragma unroll
        for (int cf = 0; cf < 2; ++cf) {
            float bv = lb2[c0 + cf * 16 + rlo];
#pragma unroll
            for (int i = 0; i < 4; ++i)
                zv[rf][cf][i] = fast_sigmoid(acc[rf][cf][i] + bv);
        }

    // ================= phase R (gate 1) =================
#pragma unroll
    for (int cf = 0; cf < 2; ++cf)
#pragma unroll
        for (int ks = 0; ks < 8; ++ks)
            bfr[cf][ks] = *(const short8*)(BT + (size_t)(128 + c0 + cf * 16 + rlo) * 256
                                           + ks * 32 + koff);
#pragma unroll
    for (int rf = 0; rf < 4; ++rf) { acc[rf][0] = zero4; acc[rf][1] = zero4; }
#pragma unroll
    for (int rf = 0; rf < 4; ++rf)
#pragma unroll
        for (int ks = 0; ks < 8; ++ks) {
            short8 af = (ks < 4)
                ? *(const short8*)&Aag[rf * 16 + rlo][ks * 32 + koff]
                : *(const short8*)&Ah0[rf * 16 + rlo][(ks - 4) * 32 + koff];
            acc[rf][0] = __builtin_amdgcn_mfma_f32_16x16x32_bf16(af, bfr[0][ks], acc[rf][0], 0, 0, 0);
            acc[rf][1] = __builtin_amdgcn_mfma_f32_16x16x32_bf16(af, bfr[1][ks], acc[rf][1], 0, 0, 0);
        }
#pragma unroll
    for (int rf = 0; rf < 4; ++rf)
#pragma unroll
        for (int cf = 0; cf < 2; ++cf) {
            int lc = c0 + cf * 16 + rlo;
            float bv = lb2[128 + lc];
#pragma unroll
            for (int i = 0; i < 4; ++i) {
                int row = rf * 16 + rbase + i;
                float r = fast_sigmoid(acc[rf][cf][i] + bv);
                Ahq[row][lc] = f2bf(r * bf2f(Ah0[row][lc]));
            }
        }
    __syncthreads();   // hq visible to all waves

    // ================= phase HT (gate 2): A = [agg | hq] =================
#pragma unroll
    for (int cf = 0; cf < 2; ++cf)
#pragma unroll
        for (int ks = 0; ks < 8; ++ks)
            bfr[cf][ks] = *(const short8*)(BT + (size_t)(256 + c0 + cf * 16 + rlo) * 256
                                           + ks * 32 + koff);
#pragma unroll
    for (int rf = 0; rf < 4; ++rf) { acc[rf][0] = zero4; acc[rf][1] = zero4; }
#pragma unroll
    for (int rf = 0; rf < 4; ++rf)
#pragma unroll
        for (int ks = 0; ks < 8; ++ks) {
            short8 af = (ks < 4)
                ? *(const short8*)&Aag[rf * 16 + rlo][ks * 32 + koff]
                : *(const short8*)&Ahq[rf * 16 + rlo][(ks - 4) * 32 + koff];
            acc[rf][0] = __builtin_amdgcn_mfma_f32_16x16x32_bf16(af, bfr[0][ks], acc[rf][0], 0, 0, 0);
            acc[rf][1] = __builtin_amdgcn_mfma_f32_16x16x32_bf16(af, bfr[1][ks], acc[rf][1], 0, 0, 0);
        }
#pragma unroll
    for (int rf = 0; rf < 4; ++rf)
#pragma unroll
        for (int cf = 0; cf < 2; ++cf) {
            int lc = c0 + cf * 16 + rlo;
            float bv = lb2[256 + lc];
#pragma unroll
            for (int i = 0; i < 4; ++i) {
                int row = rf * 16 + rbase + i;
                int grow = i0 + row;
                if (grow < n) {
                    float ht = fast_tanh(acc[rf][cf][i] + bv);
                    float z = zv[rf][cf][i];
                    float h0v = bf2f(Ah0[row][lc]);
                    hout[(size_t)grow * HD + lc] = z * h0v + (1.0f - z) * ht;
                }
            }
        }
}

__global__ __launch_bounds__(128) void pool_kernel(
        const float* __restrict__ hout, const int* __restrict__ nids,
        float* pooled, int U) {
    int t = threadIdx.x;
    float pa = 0.0f;
    for (int u = blockIdx.x; u < U; u += gridDim.x) {
        int nid = nids[u];
        pa += fmaxf(hout[(size_t)nid * HD + t], 0.0f);
    }
    atomicAdd(&pooled[t], pa);
}

__global__ __launch_bounds__(128) void decoder_kernel(
        const float* __restrict__ pooled, float invU,
        const float* __restrict__ linW, const float* __restrict__ linb,
        const float* __restrict__ dnW, const float* __restrict__ dnb,
        const float* __restrict__ outW, const float* __restrict__ outb,
        float* pred, int C) {
    __shared__ float sh[HD];
    int t = threadIdx.x;
    sh[t] = pooled[t] * invU;
    __syncthreads();
    float v = linb[t];
    for (int k = 0; k < HD; ++k) v += sh[k] * linW[k * HD + t];
    __syncthreads();
    sh[t] = v;
    __syncthreads();
    float d = dnb[t];
    for (int k = 0; k < HD; ++k) d += sh[k] * dnW[k * HD + t];
    d = fmaxf(d, 0.0f);
    __syncthreads();
    sh[t] = d;
    __syncthreads();
    if (t < C) {
        float p = outb[t];
        for (int k = 0; k < HD; ++k) p += sh[k] * outW[k * C + t];
        pred[t] = 1.0f / (1.0f + expf(-p));
    }
}

extern "C" void kernel_launch(void* const* d_in, const int* in_sizes, int n_in,
                              void* d_out, int out_size, void* d_ws, size_t ws_size,
                              hipStream_t stream) {
    const float* node_feat = (const float*)d_in[0];
    const float* edge_w    = (const float*)d_in[1];
    const float* h0        = (const float*)d_in[2];
    const float* Wz  = (const float*)d_in[3];  const float* bz  = (const float*)d_in[4];
    const float* Wr  = (const float*)d_in[5];  const float* br  = (const float*)d_in[6];
    const float* Wh  = (const float*)d_in[7];  const float* bh  = (const float*)d_in[8];
    const float* lzW = (const float*)d_in[9];  const float* lzb = (const float*)d_in[10];
    const float* lrW = (const float*)d_in[11]; const float* lrb = (const float*)d_in[12];
    const float* lhW = (const float*)d_in[13]; const float* lhb = (const float*)d_in[14];
    const float* linW= (const float*)d_in[15]; const float* linb= (const float*)d_in[16];
    const float* dnW = (const float*)d_in[17]; const float* dnb = (const float*)d_in[18];
    const float* outW= (const float*)d_in[19]; const float* outb= (const float*)d_in[20];
    const int* src  = (const int*)d_in[21];
    const int* dst  = (const int*)d_in[22];
    const int* nids = (const int*)d_in[23];

    const int N = in_sizes[2] / HD;
    const int E = in_sizes[1];
    const int U = in_sizes[23];
    const int C = in_sizes[20];
    const int NP = (N + 127) & ~127;    // row-padded
    const int NB1K = (N + 1023) / 1024; // scan blocks
    const int NR = (N + RSIZE - 1) / RSIZE;       // ranges
    const int NPAD = NR * RSIZE;
    int NEC = 64;                                  // edge chunks
    {   // keep per-chunk counts < 65536 for packed ushort ranks
        int minc = (E + 65535) / 65536;
        if (NEC < minc) NEC = minc;
    }
    const int EC = (E + NEC - 1) / NEC;

    float* out  = (float*)d_out;
    float* pred = out;          // [C]
    float* hout = out + C;      // [N,H]

    // workspace layout (16B-aligned chunks)
    char* p = (char*)d_ws;
    auto alloc = [&](size_t bytes) { char* r = p; p += (bytes + 15) & ~(size_t)15; return r; };
    float* dinv   = (float*)alloc((size_t)N * 4);
    float* pooled = (float*)alloc(HD * 4);
    int*   counts = (int*)alloc((size_t)N * 4);
    int*   row_ptr= (int*)alloc((size_t)(N + 1) * 4);
    int2*  es     = (int2*)alloc((size_t)E * 8);
    int*   bsums  = (int*)alloc((size_t)1024 * 4);
    int*   pc     = (int*)alloc((size_t)NEC * NPAD * 4);
    float* pw     = (float*)alloc((size_t)NEC * NPAD * 4);
    ushort* nfb   = (ushort*)alloc((size_t)NP * HD * 2);
    ushort* aggb  = (ushort*)alloc((size_t)NP * HD * 2);
    ushort* h0b   = (ushort*)alloc((size_t)NP * HD * 2);
    ushort* BT    = (ushort*)alloc((size_t)3 * 128 * 256 * 2);
    float* lb2    = (float*)alloc(384 * 4);

    hipMemsetAsync(pooled, 0, HD * sizeof(float), stream);

    int prep_items = N * (HD / 8);
    prep_kernel<<<(prep_items + 255) / 256, 256, 0, stream>>>(node_feat, h0, nfb, h0b, N);
    hist_lds_kernel<<<NR * NEC, 256, 0, stream>>>(dst, edge_w, pc, pw, NPAD, NR, EC, E);
    reduce_hist_kernel<<<(N + 255) / 256, 256, 0, stream>>>(pc, pw, counts, dinv,
                                                            NPAD, NEC, N);
    scan_partial_kernel<<<NB1K, 256, 0, stream>>>(counts, bsums, N);
    scan_bsums_kernel<<<1, 1024, 0, stream>>>(bsums, row_ptr + N, NB1K);
    scan_final_kernel<<<NB1K, 256, 0, stream>>>(counts, bsums, row_ptr, N);
    col_scan_kernel<<<(N + 255) / 256, 256, 0, stream>>>(row_ptr, pc, NPAD, NEC, N);
    fill2d_kernel<<<NEC * NR, 256, 0, stream>>>(src, dst, edge_w, dinv, pc,
                                                es, NPAD, NR, EC, E);
    dim3 fg(3, 16);
    fuse_weights_kernel<<<fg, 256, 0, stream>>>(Wz, Wr, Wh, lzW, lrW, lhW, BT);
    lb2_kernel<<<3, 128, 0, stream>>>(lzW, lrW, lhW, bz, br, bh, lzb, lrb, lhb, lb2);
    agg_feat_kernel<<<(N + 3) / 4, 256, 0, stream>>>(
        (const unsigned*)nfb, dinv, row_ptr, es, (unsigned*)aggb, N);
    gru_fused_kernel<<<NP / 64, 256, 0, stream>>>(aggb, h0b, BT, lb2, hout, N);
    pool_kernel<<<512, 128, 0, stream>>>(hout, nids, pooled, U);
    decoder_kernel<<<1, 128, 0, stream>>>(pooled, 1.0f / (float)U,
                                          linW, linb, dnW, dnb, outW, outb, pred, C);
}

// Round 12
// 289.180 us; speedup vs baseline: 1.1455x; 1.0519x over previous
//
#include <hip/hip_runtime.h>
#include <math.h>

// TGCN: bf16 feature-space GCN aggregation (fp32 accum) -> single fused GRU
// kernel (z,r,hq,ht in one pass; B-slice in REGISTERS per wave, A in LDS).
// CSR-by-dst built with ZERO global atomics; interleaved int2 {src,norm}
// payload. Aggregation: 2 adjacent nodes per wave (16 outstanding gathers)
// with software-pipelined es prefetch (latency-bound fix, R11 PMC).

#define HD 128
#define RBITS 13
#define RSIZE 8192          // nodes per histogram/fill range

typedef __attribute__((ext_vector_type(8))) short short8;
typedef __attribute__((ext_vector_type(4))) float f32x4;

__device__ __forceinline__ ushort f2bf(float f) {
    union { float f; unsigned u; } v; v.f = f;
    unsigned r = (v.u + 0x7FFFu + ((v.u >> 16) & 1u)) >> 16;
    return (ushort)r;
}
__device__ __forceinline__ float bf2f(ushort h) {
    union { unsigned u; float f; } v; v.u = ((unsigned)h) << 16;
    return v.f;
}
__device__ __forceinline__ float bflo(unsigned u) {
    union { unsigned u; float f; } v; v.u = u << 16; return v.f;
}
__device__ __forceinline__ float bfhi(unsigned u) {
    union { unsigned u; float f; } v; v.u = u & 0xFFFF0000u; return v.f;
}
__device__ __forceinline__ float fast_sigmoid(float x) {
    return 1.0f / (1.0f + __expf(-x));
}
__device__ __forceinline__ float fast_tanh(float x) {
    float e = __expf(-2.0f * fabsf(x));
    float m = (1.0f - e) / (1.0f + e);
    return copysignf(m, x);
}

// nf -> bf16, h0 -> bf16 (vectorized)
__global__ void prep_kernel(const float* __restrict__ nf, const float* __restrict__ h0,
                            ushort* __restrict__ nfb, ushort* __restrict__ h0b, int n) {
    int idx = blockIdx.x * 256 + threadIdx.x;
    int total8 = n * (HD / 8);
    if (idx < total8) {
        const float4* p = (const float4*)(nf + (size_t)idx * 8);
        float4 x = p[0], y = p[1];
        short8 o;
        o[0] = (short)f2bf(x.x); o[1] = (short)f2bf(x.y);
        o[2] = (short)f2bf(x.z); o[3] = (short)f2bf(x.w);
        o[4] = (short)f2bf(y.x); o[5] = (short)f2bf(y.y);
        o[6] = (short)f2bf(y.z); o[7] = (short)f2bf(y.w);
        *(short8*)(nfb + (size_t)idx * 8) = o;
        const float4* q = (const float4*)(h0 + (size_t)idx * 8);
        float4 a = q[0], b = q[1];
        short8 o2;
        o2[0] = (short)f2bf(a.x); o2[1] = (short)f2bf(a.y);
        o2[2] = (short)f2bf(a.z); o2[3] = (short)f2bf(a.w);
        o2[4] = (short)f2bf(b.x); o2[5] = (short)f2bf(b.y);
        o2[6] = (short)f2bf(b.z); o2[7] = (short)f2bf(b.w);
        *(short8*)(h0b + (size_t)idx * 8) = o2;
    }
}

// LDS-privatized histogram. Block (r = bid%NR, c = bid/NR): counts/weights of
// dst in range r over edge chunk c. Flush = plain coalesced stores.
__global__ __launch_bounds__(256) void hist_lds_kernel(
        const int* __restrict__ dst, const float* __restrict__ w,
        int* __restrict__ pc, float* __restrict__ pw,
        int NPAD, int NR, int EC, int E) {
    __shared__ int lc[RSIZE];
    __shared__ float lw[RSIZE];
    int r = blockIdx.x % NR;
    int c = blockIdx.x / NR;
    int t = threadIdx.x;
    for (int b = t; b < RSIZE; b += 256) { lc[b] = 0; lw[b] = 0.0f; }
    __syncthreads();
    int base = c * EC;
    int end = min(base + EC, E);
    int rbase = r << RBITS;
    for (int e = base + t; e < end; e += 256) {
        int d = dst[e];
        float wv = w[e];
        if ((d >> RBITS) == r) {
            atomicAdd(&lc[d - rbase], 1);
            atomicAdd(&lw[d - rbase], wv);
        }
    }
    __syncthreads();
    size_t o = (size_t)c * NPAD + rbase;
    for (int b = t; b < RSIZE; b += 256) {
        pc[o + b] = lc[b];
        pw[o + b] = lw[b];
    }
}

// counts[i] = sum_c pc[c][i];  dinv[i] = rsqrt(1 + sum_c pw[c][i])
__global__ __launch_bounds__(256) void reduce_hist_kernel(
        const int* __restrict__ pc, const float* __restrict__ pw,
        int* __restrict__ counts, float* __restrict__ dinv,
        int NPAD, int NEC, int N) {
    int i = blockIdx.x * 256 + threadIdx.x;
    if (i >= N) return;
    int ctot = 0;
    float d = 1.0f;   // self-loop
    for (int c = 0; c < NEC; ++c) {
        ctot += pc[(size_t)c * NPAD + i];
        d += pw[(size_t)c * NPAD + i];
    }
    counts[i] = ctot;
    dinv[i] = (d > 0.0f) ? rsqrtf(d) : 0.0f;
}

// ---- hierarchical scan: partial sums (1024 elems / 256-thr block) ----
__global__ __launch_bounds__(256) void scan_partial_kernel(
        const int* __restrict__ counts, int* __restrict__ bsums, int n) {
    __shared__ int ws[4];
    int b = blockIdx.x, t = threadIdx.x;
    int idx = b * 1024 + t * 4;
    int4 v = {0, 0, 0, 0};
    if (idx + 3 < n) v = *(const int4*)(counts + idx);
    else {
        if (idx < n) v.x = counts[idx];
        if (idx + 1 < n) v.y = counts[idx + 1];
        if (idx + 2 < n) v.z = counts[idx + 2];
        if (idx + 3 < n) v.w = counts[idx + 3];
    }
    int s = v.x + v.y + v.z + v.w;
    for (int off = 1; off < 64; off <<= 1) s += __shfl_xor(s, off, 64);
    if ((t & 63) == 0) ws[t >> 6] = s;
    __syncthreads();
    if (t == 0) bsums[b] = ws[0] + ws[1] + ws[2] + ws[3];
}

// scan of nb (<=1024) block sums -> exclusive; writes row_ptr[n]
__global__ __launch_bounds__(1024) void scan_bsums_kernel(
        int* __restrict__ bsums, int* __restrict__ rp_total, int nb) {
    __shared__ int ws[16];
    int t = threadIdx.x;
    int v = (t < nb) ? bsums[t] : 0;
    int lane = t & 63, wid = t >> 6;
    int x = v;
    for (int off = 1; off < 64; off <<= 1) {
        int y = __shfl_up(x, off, 64);
        if (lane >= off) x += y;
    }
    if (lane == 63) ws[wid] = x;
    __syncthreads();
    if (wid == 0) {
        int s = (lane < 16) ? ws[lane] : 0;
        for (int off = 1; off < 16; off <<= 1) {
            int y = __shfl_up(s, off, 64);
            if (lane >= off) s += y;
        }
        if (lane < 16) ws[lane] = s;
    }
    __syncthreads();
    int excl = x - v + ((wid == 0) ? 0 : ws[wid - 1]);
    if (t < nb) bsums[t] = excl;
    if (t == nb - 1) *rp_total = excl + v;
}

// final: per-block local scan + block offset -> row_ptr
__global__ __launch_bounds__(256) void scan_final_kernel(
        const int* __restrict__ counts, const int* __restrict__ bsums,
        int* __restrict__ row_ptr, int n) {
    __shared__ int ws[4];
    int b = blockIdx.x, t = threadIdx.x;
    int idx = b * 1024 + t * 4;
    int4 v = {0, 0, 0, 0};
    if (idx + 3 < n) v = *(const int4*)(counts + idx);
    else {
        if (idx < n) v.x = counts[idx];
        if (idx + 1 < n) v.y = counts[idx + 1];
        if (idx + 2 < n) v.z = counts[idx + 2];
        if (idx + 3 < n) v.w = counts[idx + 3];
    }
    int s = v.x + v.y + v.z + v.w;
    int lane = t & 63, wid = t >> 6;
    int x = s;
    for (int off = 1; off < 64; off <<= 1) {
        int y = __shfl_up(x, off, 64);
        if (lane >= off) x += y;
    }
    if (lane == 63) ws[wid] = x;
    __syncthreads();
    int woff = 0;
    for (int wv = 0; wv < wid; ++wv) woff += ws[wv];
    int run = bsums[b] + woff + x - s;
    int4 rp;
    rp.x = run; rp.y = run + v.x; rp.z = rp.y + v.y; rp.w = rp.z + v.z;
    if (idx + 3 < n) {
        *(int4*)(row_ptr + idx) = rp;
    } else {
        if (idx < n) row_ptr[idx] = rp.x;
        if (idx + 1 < n) row_ptr[idx + 1] = rp.y;
        if (idx + 2 < n) row_ptr[idx + 2] = rp.z;
        if (idx + 3 < n) row_ptr[idx + 3] = rp.w;
    }
}

// pc[c][d] (counts) -> per-chunk CSR base offsets (in place):
// pc[c][d] := row_ptr[d] + sum_{c'<c} cnt[c'][d]
__global__ __launch_bounds__(256) void col_scan_kernel(
        const int* __restrict__ row_ptr, int* __restrict__ pc,
        int NPAD, int NEC, int n) {
    int i = blockIdx.x * 256 + threadIdx.x;
    if (i >= n) return;
    int run = row_ptr[i];
    for (int c = 0; c < NEC; ++c) {
        size_t idx = (size_t)c * NPAD + i;
        int v = pc[idx];
        pc[idx] = run;
        run += v;
    }
}

// fill: block (c,r) assigns slots for chunk c's edges in range r via packed
// ushort LDS ranks; ONE interleaved int2 {src, norm} store per edge.
__global__ __launch_bounds__(256) void fill2d_kernel(
        const int* __restrict__ src, const int* __restrict__ dst,
        const float* __restrict__ w, const float* __restrict__ dinv,
        const int* __restrict__ pc, int2* __restrict__ es,
        int NPAD, int NR, int EC, int E) {
    __shared__ unsigned pk[RSIZE / 2];   // 16KB packed ushort cursors
    int r = blockIdx.x % NR;
    int c = blockIdx.x / NR;
    int t = threadIdx.x;
    for (int b = t; b < RSIZE / 2; b += 256) pk[b] = 0u;
    __syncthreads();
    int base = c * EC;
    int end = min(base + EC, E);
    int rbase = r << RBITS;
    const int* __restrict__ pco = pc + (size_t)c * NPAD;
    for (int e = base + t; e < end; e += 256) {
        int d = dst[e];
        if ((d >> RBITS) == r) {
            int dl = d - rbase;
            unsigned sh = (dl & 1) * 16;
            unsigned old = atomicAdd(&pk[dl >> 1], 1u << sh);
            int rank = (int)((old >> sh) & 0xFFFFu);
            int pos = pco[d] + rank;
            int s = src[e];
            float nv = dinv[s] * w[e] * dinv[d];
            int2 ev;
            ev.x = s;
            ev.y = __float_as_int(nv);
            es[pos] = ev;
        }
    }
}

// Fused-weight build, parallel+coalesced. grid (3,16), 256 thr.
__global__ __launch_bounds__(256) void fuse_weights_kernel(
        const float* __restrict__ Wz, const float* __restrict__ Wr,
        const float* __restrict__ Wh,
        const float* __restrict__ lzW, const float* __restrict__ lrW,
        const float* __restrict__ lhW,
        ushort* __restrict__ BT) {
    int g = blockIdx.x, kt = blockIdx.y;
    const float* W  = (g == 0) ? Wz  : (g == 1) ? Wr  : Wh;
    const float* lW = (g == 0) ? lzW : (g == 1) ? lrW : lhW;
    int t = threadIdx.x;
    int j = t & 127, kh = t >> 7;          // kh in {0,1}
    int k0 = kt * 8 + kh * 4;
    float m0 = 0.f, m1 = 0.f, m2 = 0.f, m3 = 0.f;
    for (int mm = 0; mm < 128; ++mm) {
        float lv = lW[mm * 128 + j];       // coalesced across j
        m0 += W[(k0 + 0) * 128 + mm] * lv; // wave-uniform -> broadcast
        m1 += W[(k0 + 1) * 128 + mm] * lv;
        m2 += W[(k0 + 2) * 128 + mm] * lv;
        m3 += W[(k0 + 3) * 128 + mm] * lv;
    }
    ushort* dstc = BT + ((size_t)g * 128 + j) * 256;
    dstc[k0 + 0] = f2bf(m0); dstc[k0 + 1] = f2bf(m1);
    dstc[k0 + 2] = f2bf(m2); dstc[k0 + 3] = f2bf(m3);
#pragma unroll
    for (int u = 0; u < 4; ++u) {
        int mm = k0 + u;
        dstc[128 + mm] = f2bf(lW[(128 + mm) * 128 + j]);
    }
}

// lb2[g][j] = lgb[j] + sum_m bg[m]*lgW_top[m][j]
__global__ __launch_bounds__(128) void lb2_kernel(
        const float* __restrict__ lzW, const float* __restrict__ lrW,
        const float* __restrict__ lhW,
        const float* __restrict__ bz, const float* __restrict__ br,
        const float* __restrict__ bh,
        const float* __restrict__ lzb, const float* __restrict__ lrb,
        const float* __restrict__ lhb,
        float* __restrict__ lb2) {
    int g = blockIdx.x, j = threadIdx.x;
    const float* lW = (g == 0) ? lzW : (g == 1) ? lrW : lhW;
    const float* bg = (g == 0) ? bz  : (g == 1) ? br  : bh;
    const float* lb = (g == 0) ? lzb : (g == 1) ? lrb : lhb;
    float s = lb[j];
    for (int mm = 0; mm < 128; ++mm) s += bg[mm] * lW[mm * 128 + j];
    lb2[g * 128 + j] = s;
}

// agg: 2 adjacent nodes per wave, dual 8-deep gather pipelines, es prefetch.
// aggb[i,:] = bf16( dinv[i]^2 * nfb[i,:] + sum_e norm[e] * nfb[src[e],:] )
__global__ __launch_bounds__(256) void agg_feat_kernel(
        const unsigned* __restrict__ nfb32, const float* __restrict__ dinv,
        const int* __restrict__ row_ptr, const int2* __restrict__ es,
        unsigned* __restrict__ aggb32, int n) {
    int t = threadIdx.x & 63;            // column pair
    int grp = threadIdx.x >> 6;
    int iA = blockIdx.x * 8 + grp * 2;
    if (iA >= n) return;
    int iB = iA + 1;
    bool hasB = iB < n;
    float dA = dinv[iA];
    float dB = hasB ? dinv[iB] : 0.0f;
    unsigned sA = nfb32[(size_t)iA * 64 + t];
    unsigned sB = hasB ? nfb32[(size_t)iB * 64 + t] : 0u;
    float a0A = dA * dA * bflo(sA), a1A = dA * dA * bfhi(sA);
    float a0B = dB * dB * bflo(sB), a1B = dB * dB * bfhi(sB);
    int eA = row_ptr[iA];
    int e1A = row_ptr[iA + 1];
    int eB = e1A;                                  // CSR adjacency
    int e1B = hasB ? row_ptr[iB + 1] : e1A;

    int2 zed; zed.x = 0; zed.y = 0;
    int2 bufA[8], bufB[8];
#pragma unroll
    for (int u = 0; u < 8; ++u) {
        int ea = eA + u;
        bufA[u] = (ea < e1A) ? es[ea] : zed;
        int eb = eB + u;
        bufB[u] = (eb < e1B) ? es[eb] : zed;
    }
    while (eA < e1A || eB < e1B) {
        // issue 16 independent gathers from current metadata
        unsigned vA[8], vB[8];
        float wA[8], wB[8];
#pragma unroll
        for (int u = 0; u < 8; ++u) {
            vA[u] = nfb32[(size_t)bufA[u].x * 64 + t];
            wA[u] = __int_as_float(bufA[u].y);
            vB[u] = nfb32[(size_t)bufB[u].x * 64 + t];
            wB[u] = __int_as_float(bufB[u].y);
        }
        int nA = eA + 8, nB = eB + 8;
        // prefetch next es batches while gathers are in flight
#pragma unroll
        for (int u = 0; u < 8; ++u) {
            int ea = nA + u;
            bufA[u] = (eA < e1A && ea < e1A) ? es[ea] : zed;
            int eb = nB + u;
            bufB[u] = (eB < e1B && eb < e1B) ? es[eb] : zed;
        }
#pragma unroll
        for (int u = 0; u < 8; ++u) {
            a0A += wA[u] * bflo(vA[u]);
            a1A += wA[u] * bfhi(vA[u]);
            a0B += wB[u] * bflo(vB[u]);
            a1B += wB[u] * bfhi(vB[u]);
        }
        eA = min(nA, e1A);
        eB = min(nB, e1B);
    }
    aggb32[(size_t)iA * 64 + t] = (unsigned)f2bf(a0A) | ((unsigned)f2bf(a1A) << 16);
    if (hasB)
        aggb32[(size_t)iB * 64 + t] = (unsigned)f2bf(a0B) | ((unsigned)f2bf(a1B) << 16);
}

// Fused GRU: 64-row tile per block, 4 waves; wave w owns a 32-col slice and
// ALL 64 rows. Per phase: 16 independent B-loads into REGISTERS (one latency
// round), then 32 LDS A-reads + 64 MFMAs. hq goes to a 3rd LDS buffer.
__global__ __launch_bounds__(256) void gru_fused_kernel(
        const ushort* __restrict__ aggb, const ushort* __restrict__ h0b,
        const ushort* __restrict__ BT, const float* __restrict__ lb2,
        float* __restrict__ hout, int n) {
    __shared__ ushort Aag[64][136];   // agg tile (pad 8 -> 2-way alias, free)
    __shared__ ushort Ah0[64][136];   // h0 tile (bf16)
    __shared__ ushort Ahq[64][136];   // h0*r tile
    int t = threadIdx.x;
    int i0 = blockIdx.x * 64;

    for (int c = t; c < 1024; c += 256) {
        int row = c >> 4, c8 = c & 15;
        size_t gp = (size_t)(i0 + row) * HD + c8 * 8;
        *(short8*)&Aag[row][c8 * 8] = *(const short8*)(aggb + gp);
        *(short8*)&Ah0[row][c8 * 8] = *(const short8*)(h0b + gp);
    }
    __syncthreads();

    int w = t >> 6, lane = t & 63;
    int rlo = lane & 15, koff = (lane >> 4) * 8, rbase = (lane >> 4) * 4;
    int c0 = w * 32;                    // wave's column base within gate

    const f32x4 zero4 = {0.f, 0.f, 0.f, 0.f};
    short8 bfr[2][8];
    f32x4 acc[4][2];
    float zv[4][2][4];

    // ================= phase Z (gate 0) =================
#pragma unroll
    for (int cf = 0; cf < 2; ++cf)
#pragma unroll
        for (int ks = 0; ks < 8; ++ks)
            bfr[cf][ks] = *(const short8*)(BT + (size_t)(c0 + cf * 16 + rlo) * 256
                                           + ks * 32 + koff);
#pragma unroll
    for (int rf = 0; rf < 4; ++rf) { acc[rf][0] = zero4; acc[rf][1] = zero4; }
#pragma unroll
    for (int rf = 0; rf < 4; ++rf)
#pragma unroll
        for (int ks = 0; ks < 8; ++ks) {
            short8 af = (ks < 4)
                ? *(const short8*)&Aag[rf * 16 + rlo][ks * 32 + koff]
                : *(const short8*)&Ah0[rf * 16 + rlo][(ks - 4) * 32 + koff];
            acc[rf][0] = __builtin_amdgcn_mfma_f32_16x16x32_bf16(af, bfr[0][ks], acc[rf][0], 0, 0, 0);
            acc[rf][1] = __builtin_amdgcn_mfma_f32_16x16x32_bf16(af, bfr[1][ks], acc[rf][1], 0, 0, 0);
        }
#pragma unroll
    for (int rf = 0; rf < 4; ++rf)
#pragma unroll
        for (int cf = 0; cf < 2; ++cf) {
            float bv = lb2[c0 + cf * 16 + rlo];
#pragma unroll
            for (int i = 0; i < 4; ++i)
                zv[rf][cf][i] = fast_sigmoid(acc[rf][cf][i] + bv);
        }

    // ================= phase R (gate 1) =================
#pragma unroll
    for (int cf = 0; cf < 2; ++cf)
#pragma unroll
        for (int ks = 0; ks < 8; ++ks)
            bfr[cf][ks] = *(const short8*)(BT + (size_t)(128 + c0 + cf * 16 + rlo) * 256
                                           + ks * 32 + koff);
#pragma unroll
    for (int rf = 0; rf < 4; ++rf) { acc[rf][0] = zero4; acc[rf][1] = zero4; }
#pragma unroll
    for (int rf = 0; rf < 4; ++rf)
#pragma unroll
        for (int ks = 0; ks < 8; ++ks) {
            short8 af = (ks < 4)
                ? *(const short8*)&Aag[rf * 16 + rlo][ks * 32 + koff]
                : *(const short8*)&Ah0[rf * 16 + rlo][(ks - 4) * 32 + koff];
            acc[rf][0] = __builtin_amdgcn_mfma_f32_16x16x32_bf16(af, bfr[0][ks], acc[rf][0], 0, 0, 0);
            acc[rf][1] = __builtin_amdgcn_mfma_f32_16x16x32_bf16(af, bfr[1][ks], acc[rf][1], 0, 0, 0);
        }
#pragma unroll
    for (int rf = 0; rf < 4; ++rf)
#pragma unroll
        for (int cf = 0; cf < 2; ++cf) {
            int lc = c0 + cf * 16 + rlo;
            float bv = lb2[128 + lc];
#pragma unroll
            for (int i = 0; i < 4; ++i) {
                int row = rf * 16 + rbase + i;
                float r = fast_sigmoid(acc[rf][cf][i] + bv);
                Ahq[row][lc] = f2bf(r * bf2f(Ah0[row][lc]));
            }
        }
    __syncthreads();   // hq visible to all waves

    // ================= phase HT (gate 2): A = [agg | hq] =================
#pragma unroll
    for (int cf = 0; cf < 2; ++cf)
#pragma unroll
        for (int ks = 0; ks < 8; ++ks)
            bfr[cf][ks] = *(const short8*)(BT + (size_t)(256 + c0 + cf * 16 + rlo) * 256
                                           + ks * 32 + koff);
#pragma unroll
    for (int rf = 0; rf < 4; ++rf) { acc[rf][0] = zero4; acc[rf][1] = zero4; }
#pragma unroll
    for (int rf = 0; rf < 4; ++rf)
#pragma unroll
        for (int ks = 0; ks < 8; ++ks) {
            short8 af = (ks < 4)
                ? *(const short8*)&Aag[rf * 16 + rlo][ks * 32 + koff]
                : *(const short8*)&Ahq[rf * 16 + rlo][(ks - 4) * 32 + koff];
            acc[rf][0] = __builtin_amdgcn_mfma_f32_16x16x32_bf16(af, bfr[0][ks], acc[rf][0], 0, 0, 0);
            acc[rf][1] = __builtin_amdgcn_mfma_f32_16x16x32_bf16(af, bfr[1][ks], acc[rf][1], 0, 0, 0);
        }
#pragma unroll
    for (int rf = 0; rf < 4; ++rf)
#pragma unroll
        for (int cf = 0; cf < 2; ++cf) {
            int lc = c0 + cf * 16 + rlo;
            float bv = lb2[256 + lc];
#pragma unroll
            for (int i = 0; i < 4; ++i) {
                int row = rf * 16 + rbase + i;
                int grow = i0 + row;
                if (grow < n) {
                    float ht = fast_tanh(acc[rf][cf][i] + bv);
                    float z = zv[rf][cf][i];
                    float h0v = bf2f(Ah0[row][lc]);
                    hout[(size_t)grow * HD + lc] = z * h0v + (1.0f - z) * ht;
                }
            }
        }
}

__global__ __launch_bounds__(128) void pool_kernel(
        const float* __restrict__ hout, const int* __restrict__ nids,
        float* pooled, int U) {
    int t = threadIdx.x;
    float pa = 0.0f;
    for (int u = blockIdx.x; u < U; u += gridDim.x) {
        int nid = nids[u];
        pa += fmaxf(hout[(size_t)nid * HD + t], 0.0f);
    }
    atomicAdd(&pooled[t], pa);
}

__global__ __launch_bounds__(128) void decoder_kernel(
        const float* __restrict__ pooled, float invU,
        const float* __restrict__ linW, const float* __restrict__ linb,
        const float* __restrict__ dnW, const float* __restrict__ dnb,
        const float* __restrict__ outW, const float* __restrict__ outb,
        float* pred, int C) {
    __shared__ float sh[HD];
    int t = threadIdx.x;
    sh[t] = pooled[t] * invU;
    __syncthreads();
    float v = linb[t];
    for (int k = 0; k < HD; ++k) v += sh[k] * linW[k * HD + t];
    __syncthreads();
    sh[t] = v;
    __syncthreads();
    float d = dnb[t];
    for (int k = 0; k < HD; ++k) d += sh[k] * dnW[k * HD + t];
    d = fmaxf(d, 0.0f);
    __syncthreads();
    sh[t] = d;
    __syncthreads();
    if (t < C) {
        float p = outb[t];
        for (int k = 0; k < HD; ++k) p += sh[k] * outW[k * C + t];
        pred[t] = 1.0f / (1.0f + expf(-p));
    }
}

extern "C" void kernel_launch(void* const* d_in, const int* in_sizes, int n_in,
                              void* d_out, int out_size, void* d_ws, size_t ws_size,
                              hipStream_t stream) {
    const float* node_feat = (const float*)d_in[0];
    const float* edge_w    = (const float*)d_in[1];
    const float* h0        = (const float*)d_in[2];
    const float* Wz  = (const float*)d_in[3];  const float* bz  = (const float*)d_in[4];
    const float* Wr  = (const float*)d_in[5];  const float* br  = (const float*)d_in[6];
    const float* Wh  = (const float*)d_in[7];  const float* bh  = (const float*)d_in[8];
    const float* lzW = (const float*)d_in[9];  const float* lzb = (const float*)d_in[10];
    const float* lrW = (const float*)d_in[11]; const float* lrb = (const float*)d_in[12];
    const float* lhW = (const float*)d_in[13]; const float* lhb = (const float*)d_in[14];
    const float* linW= (const float*)d_in[15]; const float* linb= (const float*)d_in[16];
    const float* dnW = (const float*)d_in[17]; const float* dnb = (const float*)d_in[18];
    const float* outW= (const float*)d_in[19]; const float* outb= (const float*)d_in[20];
    const int* src  = (const int*)d_in[21];
    const int* dst  = (const int*)d_in[22];
    const int* nids = (const int*)d_in[23];

    const int N = in_sizes[2] / HD;
    const int E = in_sizes[1];
    const int U = in_sizes[23];
    const int C = in_sizes[20];
    const int NP = (N + 127) & ~127;    // row-padded
    const int NB1K = (N + 1023) / 1024; // scan blocks
    const int NR = (N + RSIZE - 1) / RSIZE;       // ranges
    const int NPAD = NR * RSIZE;
    int NEC = 64;                                  // edge chunks
    {   // keep per-chunk counts < 65536 for packed ushort ranks
        int minc = (E + 65535) / 65536;
        if (NEC < minc) NEC = minc;
    }
    const int EC = (E + NEC - 1) / NEC;

    float* out  = (float*)d_out;
    float* pred = out;          // [C]
    float* hout = out + C;      // [N,H]

    // workspace layout (16B-aligned chunks)
    char* p = (char*)d_ws;
    auto alloc = [&](size_t bytes) { char* r = p; p += (bytes + 15) & ~(size_t)15; return r; };
    float* dinv   = (float*)alloc((size_t)N * 4);
    float* pooled = (float*)alloc(HD * 4);
    int*   counts = (int*)alloc((size_t)N * 4);
    int*   row_ptr= (int*)alloc((size_t)(N + 1) * 4);
    int2*  es     = (int2*)alloc((size_t)E * 8);
    int*   bsums  = (int*)alloc((size_t)1024 * 4);
    int*   pc     = (int*)alloc((size_t)NEC * NPAD * 4);
    float* pw     = (float*)alloc((size_t)NEC * NPAD * 4);
    ushort* nfb   = (ushort*)alloc((size_t)NP * HD * 2);
    ushort* aggb  = (ushort*)alloc((size_t)NP * HD * 2);
    ushort* h0b   = (ushort*)alloc((size_t)NP * HD * 2);
    ushort* BT    = (ushort*)alloc((size_t)3 * 128 * 256 * 2);
    float* lb2    = (float*)alloc(384 * 4);

    hipMemsetAsync(pooled, 0, HD * sizeof(float), stream);

    int prep_items = N * (HD / 8);
    prep_kernel<<<(prep_items + 255) / 256, 256, 0, stream>>>(node_feat, h0, nfb, h0b, N);
    hist_lds_kernel<<<NR * NEC, 256, 0, stream>>>(dst, edge_w, pc, pw, NPAD, NR, EC, E);
    reduce_hist_kernel<<<(N + 255) / 256, 256, 0, stream>>>(pc, pw, counts, dinv,
                                                            NPAD, NEC, N);
    scan_partial_kernel<<<NB1K, 256, 0, stream>>>(counts, bsums, N);
    scan_bsums_kernel<<<1, 1024, 0, stream>>>(bsums, row_ptr + N, NB1K);
    scan_final_kernel<<<NB1K, 256, 0, stream>>>(counts, bsums, row_ptr, N);
    col_scan_kernel<<<(N + 255) / 256, 256, 0, stream>>>(row_ptr, pc, NPAD, NEC, N);
    fill2d_kernel<<<NEC * NR, 256, 0, stream>>>(src, dst, edge_w, dinv, pc,
                                                es, NPAD, NR, EC, E);
    dim3 fg(3, 16);
    fuse_weights_kernel<<<fg, 256, 0, stream>>>(Wz, Wr, Wh, lzW, lrW, lhW, BT);
    lb2_kernel<<<3, 128, 0, stream>>>(lzW, lrW, lhW, bz, br, bh, lzb, lrb, lhb, lb2);
    agg_feat_kernel<<<(N + 7) / 8, 256, 0, stream>>>(
        (const unsigned*)nfb, dinv, row_ptr, es, (unsigned*)aggb, N);
    gru_fused_kernel<<<NP / 64, 256, 0, stream>>>(aggb, h0b, BT, lb2, hout, N);
    pool_kernel<<<512, 128, 0, stream>>>(hout, nids, pooled, U);
    decoder_kernel<<<1, 128, 0, stream>>>(pooled, 1.0f / (float)U,
                                          linW, linb, dnW, dnb, outW, outb, pred, C);
}

// Round 13
// 270.127 us; speedup vs baseline: 1.2263x; 1.0705x over previous
//
#include <hip/hip_runtime.h>
#include <math.h>

// TGCN: bf16 feature-space GCN aggregation (fp32 accum) -> single fused GRU
// kernel (z,r,hq,ht in one pass; B-slice in REGISTERS per wave, A in LDS).
// CSR-by-dst built with ZERO global atomics; interleaved int2 {src, w*dinv_s}
// payload (dinv_d applied in agg epilogue). fill: LDS-preloaded per-range
// offsets + packed ushort ranks, 512 thr.

#define HD 128
#define RBITS 13
#define RSIZE 8192          // nodes per histogram/fill range

typedef __attribute__((ext_vector_type(8))) short short8;
typedef __attribute__((ext_vector_type(4))) float f32x4;

__device__ __forceinline__ ushort f2bf(float f) {
    union { float f; unsigned u; } v; v.f = f;
    unsigned r = (v.u + 0x7FFFu + ((v.u >> 16) & 1u)) >> 16;
    return (ushort)r;
}
__device__ __forceinline__ float bf2f(ushort h) {
    union { unsigned u; float f; } v; v.u = ((unsigned)h) << 16;
    return v.f;
}
__device__ __forceinline__ float bflo(unsigned u) {
    union { unsigned u; float f; } v; v.u = u << 16; return v.f;
}
__device__ __forceinline__ float bfhi(unsigned u) {
    union { unsigned u; float f; } v; v.u = u & 0xFFFF0000u; return v.f;
}
__device__ __forceinline__ float fast_sigmoid(float x) {
    return 1.0f / (1.0f + __expf(-x));
}
__device__ __forceinline__ float fast_tanh(float x) {
    float e = __expf(-2.0f * fabsf(x));
    float m = (1.0f - e) / (1.0f + e);
    return copysignf(m, x);
}

// nf -> bf16, h0 -> bf16 (vectorized)
__global__ void prep_kernel(const float* __restrict__ nf, const float* __restrict__ h0,
                            ushort* __restrict__ nfb, ushort* __restrict__ h0b, int n) {
    int idx = blockIdx.x * 256 + threadIdx.x;
    int total8 = n * (HD / 8);
    if (idx < total8) {
        const float4* p = (const float4*)(nf + (size_t)idx * 8);
        float4 x = p[0], y = p[1];
        short8 o;
        o[0] = (short)f2bf(x.x); o[1] = (short)f2bf(x.y);
        o[2] = (short)f2bf(x.z); o[3] = (short)f2bf(x.w);
        o[4] = (short)f2bf(y.x); o[5] = (short)f2bf(y.y);
        o[6] = (short)f2bf(y.z); o[7] = (short)f2bf(y.w);
        *(short8*)(nfb + (size_t)idx * 8) = o;
        const float4* q = (const float4*)(h0 + (size_t)idx * 8);
        float4 a = q[0], b = q[1];
        short8 o2;
        o2[0] = (short)f2bf(a.x); o2[1] = (short)f2bf(a.y);
        o2[2] = (short)f2bf(a.z); o2[3] = (short)f2bf(a.w);
        o2[4] = (short)f2bf(b.x); o2[5] = (short)f2bf(b.y);
        o2[6] = (short)f2bf(b.z); o2[7] = (short)f2bf(b.w);
        *(short8*)(h0b + (size_t)idx * 8) = o2;
    }
}

// LDS-privatized histogram. Block (r = bid%NR, c = bid/NR): counts/weights of
// dst in range r over edge chunk c. Flush = plain coalesced stores.
__global__ __launch_bounds__(256) void hist_lds_kernel(
        const int* __restrict__ dst, const float* __restrict__ w,
        int* __restrict__ pc, float* __restrict__ pw,
        int NPAD, int NR, int EC, int E) {
    __shared__ int lc[RSIZE];
    __shared__ float lw[RSIZE];
    int r = blockIdx.x % NR;
    int c = blockIdx.x / NR;
    int t = threadIdx.x;
    for (int b = t; b < RSIZE; b += 256) { lc[b] = 0; lw[b] = 0.0f; }
    __syncthreads();
    int base = c * EC;
    int end = min(base + EC, E);
    int rbase = r << RBITS;
    for (int e = base + t; e < end; e += 256) {
        int d = dst[e];
        float wv = w[e];
        if ((d >> RBITS) == r) {
            atomicAdd(&lc[d - rbase], 1);
            atomicAdd(&lw[d - rbase], wv);
        }
    }
    __syncthreads();
    size_t o = (size_t)c * NPAD + rbase;
    for (int b = t; b < RSIZE; b += 256) {
        pc[o + b] = lc[b];
        pw[o + b] = lw[b];
    }
}

// counts[i] = sum_c pc[c][i];  dinv[i] = rsqrt(1 + sum_c pw[c][i])
__global__ __launch_bounds__(256) void reduce_hist_kernel(
        const int* __restrict__ pc, const float* __restrict__ pw,
        int* __restrict__ counts, float* __restrict__ dinv,
        int NPAD, int NEC, int N) {
    int i = blockIdx.x * 256 + threadIdx.x;
    if (i >= N) return;
    int ctot = 0;
    float d = 1.0f;   // self-loop
    for (int c = 0; c < NEC; ++c) {
        ctot += pc[(size_t)c * NPAD + i];
        d += pw[(size_t)c * NPAD + i];
    }
    counts[i] = ctot;
    dinv[i] = (d > 0.0f) ? rsqrtf(d) : 0.0f;
}

// ---- hierarchical scan: partial sums (1024 elems / 256-thr block) ----
__global__ __launch_bounds__(256) void scan_partial_kernel(
        const int* __restrict__ counts, int* __restrict__ bsums, int n) {
    __shared__ int ws[4];
    int b = blockIdx.x, t = threadIdx.x;
    int idx = b * 1024 + t * 4;
    int4 v = {0, 0, 0, 0};
    if (idx + 3 < n) v = *(const int4*)(counts + idx);
    else {
        if (idx < n) v.x = counts[idx];
        if (idx + 1 < n) v.y = counts[idx + 1];
        if (idx + 2 < n) v.z = counts[idx + 2];
        if (idx + 3 < n) v.w = counts[idx + 3];
    }
    int s = v.x + v.y + v.z + v.w;
    for (int off = 1; off < 64; off <<= 1) s += __shfl_xor(s, off, 64);
    if ((t & 63) == 0) ws[t >> 6] = s;
    __syncthreads();
    if (t == 0) bsums[b] = ws[0] + ws[1] + ws[2] + ws[3];
}

// scan of nb (<=1024) block sums -> exclusive; writes row_ptr[n]
__global__ __launch_bounds__(1024) void scan_bsums_kernel(
        int* __restrict__ bsums, int* __restrict__ rp_total, int nb) {
    __shared__ int ws[16];
    int t = threadIdx.x;
    int v = (t < nb) ? bsums[t] : 0;
    int lane = t & 63, wid = t >> 6;
    int x = v;
    for (int off = 1; off < 64; off <<= 1) {
        int y = __shfl_up(x, off, 64);
        if (lane >= off) x += y;
    }
    if (lane == 63) ws[wid] = x;
    __syncthreads();
    if (wid == 0) {
        int s = (lane < 16) ? ws[lane] : 0;
        for (int off = 1; off < 16; off <<= 1) {
            int y = __shfl_up(s, off, 64);
            if (lane >= off) s += y;
        }
        if (lane < 16) ws[lane] = s;
    }
    __syncthreads();
    int excl = x - v + ((wid == 0) ? 0 : ws[wid - 1]);
    if (t < nb) bsums[t] = excl;
    if (t == nb - 1) *rp_total = excl + v;
}

// final: per-block local scan + block offset -> row_ptr
__global__ __launch_bounds__(256) void scan_final_kernel(
        const int* __restrict__ counts, const int* __restrict__ bsums,
        int* __restrict__ row_ptr, int n) {
    __shared__ int ws[4];
    int b = blockIdx.x, t = threadIdx.x;
    int idx = b * 1024 + t * 4;
    int4 v = {0, 0, 0, 0};
    if (idx + 3 < n) v = *(const int4*)(counts + idx);
    else {
        if (idx < n) v.x = counts[idx];
        if (idx + 1 < n) v.y = counts[idx + 1];
        if (idx + 2 < n) v.z = counts[idx + 2];
        if (idx + 3 < n) v.w = counts[idx + 3];
    }
    int s = v.x + v.y + v.z + v.w;
    int lane = t & 63, wid = t >> 6;
    int x = s;
    for (int off = 1; off < 64; off <<= 1) {
        int y = __shfl_up(x, off, 64);
        if (lane >= off) x += y;
    }
    if (lane == 63) ws[wid] = x;
    __syncthreads();
    int woff = 0;
    for (int wv = 0; wv < wid; ++wv) woff += ws[wv];
    int run = bsums[b] + woff + x - s;
    int4 rp;
    rp.x = run; rp.y = run + v.x; rp.z = rp.y + v.y; rp.w = rp.z + v.z;
    if (idx + 3 < n) {
        *(int4*)(row_ptr + idx) = rp;
    } else {
        if (idx < n) row_ptr[idx] = rp.x;
        if (idx + 1 < n) row_ptr[idx + 1] = rp.y;
        if (idx + 2 < n) row_ptr[idx + 2] = rp.z;
        if (idx + 3 < n) row_ptr[idx + 3] = rp.w;
    }
}

// pc[c][d] (counts) -> per-chunk CSR base offsets (in place):
// pc[c][d] := row_ptr[d] + sum_{c'<c} cnt[c'][d]
__global__ __launch_bounds__(256) void col_scan_kernel(
        const int* __restrict__ row_ptr, int* __restrict__ pc,
        int NPAD, int NEC, int n) {
    int i = blockIdx.x * 256 + threadIdx.x;
    if (i >= n) return;
    int run = row_ptr[i];
    for (int c = 0; c < NEC; ++c) {
        size_t idx = (size_t)c * NPAD + i;
        int v = pc[idx];
        pc[idx] = run;
        run += v;
    }
}

// fill: block (c,r); pco range-slice preloaded into LDS (kills the per-edge
// random global read); packed ushort ranks; ONE int2 {src, w*dinv_s} store.
__global__ __launch_bounds__(512) void fill2d_kernel(
        const int* __restrict__ src, const int* __restrict__ dst,
        const float* __restrict__ w, const float* __restrict__ dinv,
        const int* __restrict__ pc, int2* __restrict__ es,
        int NPAD, int NR, int EC, int E) {
    __shared__ int po[RSIZE];            // 32KB preloaded base offsets
    __shared__ unsigned pk[RSIZE / 2];   // 16KB packed ushort cursors
    int r = blockIdx.x % NR;
    int c = blockIdx.x / NR;
    int t = threadIdx.x;
    const int* __restrict__ pco = pc + (size_t)c * NPAD + (r << RBITS);
    for (int b = t; b < RSIZE / 2; b += 512) pk[b] = 0u;
    for (int b = t; b < RSIZE; b += 512) po[b] = pco[b];
    __syncthreads();
    int base = c * EC;
    int end = min(base + EC, E);
    int rbase = r << RBITS;
    for (int e = base + t; e < end; e += 512) {
        int d = dst[e];
        if ((d >> RBITS) == r) {
            int dl = d - rbase;
            unsigned sh = (dl & 1) * 16;
            unsigned old = atomicAdd(&pk[dl >> 1], 1u << sh);
            int rank = (int)((old >> sh) & 0xFFFFu);
            int pos = po[dl] + rank;
            int s = src[e];
            float nv = dinv[s] * w[e];        // dinv[d] applied in agg epilogue
            int2 ev;
            ev.x = s;
            ev.y = __float_as_int(nv);
            es[pos] = ev;
        }
    }
}

// Fused-weight build, parallel+coalesced. grid (3,16), 256 thr.
__global__ __launch_bounds__(256) void fuse_weights_kernel(
        const float* __restrict__ Wz, const float* __restrict__ Wr,
        const float* __restrict__ Wh,
        const float* __restrict__ lzW, const float* __restrict__ lrW,
        const float* __restrict__ lhW,
        ushort* __restrict__ BT) {
    int g = blockIdx.x, kt = blockIdx.y;
    const float* W  = (g == 0) ? Wz  : (g == 1) ? Wr  : Wh;
    const float* lW = (g == 0) ? lzW : (g == 1) ? lrW : lhW;
    int t = threadIdx.x;
    int j = t & 127, kh = t >> 7;          // kh in {0,1}
    int k0 = kt * 8 + kh * 4;
    float m0 = 0.f, m1 = 0.f, m2 = 0.f, m3 = 0.f;
    for (int mm = 0; mm < 128; ++mm) {
        float lv = lW[mm * 128 + j];       // coalesced across j
        m0 += W[(k0 + 0) * 128 + mm] * lv; // wave-uniform -> broadcast
        m1 += W[(k0 + 1) * 128 + mm] * lv;
        m2 += W[(k0 + 2) * 128 + mm] * lv;
        m3 += W[(k0 + 3) * 128 + mm] * lv;
    }
    ushort* dstc = BT + ((size_t)g * 128 + j) * 256;
    dstc[k0 + 0] = f2bf(m0); dstc[k0 + 1] = f2bf(m1);
    dstc[k0 + 2] = f2bf(m2); dstc[k0 + 3] = f2bf(m3);
#pragma unroll
    for (int u = 0; u < 4; ++u) {
        int mm = k0 + u;
        dstc[128 + mm] = f2bf(lW[(128 + mm) * 128 + j]);
    }
}

// lb2[g][j] = lgb[j] + sum_m bg[m]*lgW_top[m][j]
__global__ __launch_bounds__(128) void lb2_kernel(
        const float* __restrict__ lzW, const float* __restrict__ lrW,
        const float* __restrict__ lhW,
        const float* __restrict__ bz, const float* __restrict__ br,
        const float* __restrict__ bh,
        const float* __restrict__ lzb, const float* __restrict__ lrb,
        const float* __restrict__ lhb,
        float* __restrict__ lb2) {
    int g = blockIdx.x, j = threadIdx.x;
    const float* lW = (g == 0) ? lzW : (g == 1) ? lrW : lhW;
    const float* bg = (g == 0) ? bz  : (g == 1) ? br  : bh;
    const float* lb = (g == 0) ? lzb : (g == 1) ? lrb : lhb;
    float s = lb[j];
    for (int mm = 0; mm < 128; ++mm) s += bg[mm] * lW[mm * 128 + j];
    lb2[g * 128 + j] = s;
}

// agg: 2 adjacent nodes per wave, dual 8-deep gather pipelines, es prefetch.
// aggb[i,:] = bf16( dinv_i * (dinv_i*nf_i + sum_e (w*dinv_s)*nf_s) )
__global__ __launch_bounds__(256) void agg_feat_kernel(
        const unsigned* __restrict__ nfb32, const float* __restrict__ dinv,
        const int* __restrict__ row_ptr, const int2* __restrict__ es,
        unsigned* __restrict__ aggb32, int n) {
    int t = threadIdx.x & 63;            // column pair
    int grp = threadIdx.x >> 6;
    int iA = blockIdx.x * 8 + grp * 2;
    if (iA >= n) return;
    int iB = iA + 1;
    bool hasB = iB < n;
    float dA = dinv[iA];
    float dB = hasB ? dinv[iB] : 0.0f;
    unsigned sA = nfb32[(size_t)iA * 64 + t];
    unsigned sB = hasB ? nfb32[(size_t)iB * 64 + t] : 0u;
    float a0A = dA * bflo(sA), a1A = dA * bfhi(sA);
    float a0B = dB * bflo(sB), a1B = dB * bfhi(sB);
    int eA = row_ptr[iA];
    int e1A = row_ptr[iA + 1];
    int eB = e1A;                                  // CSR adjacency
    int e1B = hasB ? row_ptr[iB + 1] : e1A;

    int2 zed; zed.x = 0; zed.y = 0;
    int2 bufA[8], bufB[8];
#pragma unroll
    for (int u = 0; u < 8; ++u) {
        int ea = eA + u;
        bufA[u] = (ea < e1A) ? es[ea] : zed;
        int eb = eB + u;
        bufB[u] = (eb < e1B) ? es[eb] : zed;
    }
    while (eA < e1A || eB < e1B) {
        // issue 16 independent gathers from current metadata
        unsigned vA[8], vB[8];
        float wA[8], wB[8];
#pragma unroll
        for (int u = 0; u < 8; ++u) {
            vA[u] = nfb32[(size_t)bufA[u].x * 64 + t];
            wA[u] = __int_as_float(bufA[u].y);
            vB[u] = nfb32[(size_t)bufB[u].x * 64 + t];
            wB[u] = __int_as_float(bufB[u].y);
        }
        int nA = eA + 8, nB = eB + 8;
        // prefetch next es batches while gathers are in flight
#pragma unroll
        for (int u = 0; u < 8; ++u) {
            int ea = nA + u;
            bufA[u] = (eA < e1A && ea < e1A) ? es[ea] : zed;
            int eb = nB + u;
            bufB[u] = (eB < e1B && eb < e1B) ? es[eb] : zed;
        }
#pragma unroll
        for (int u = 0; u < 8; ++u) {
            a0A += wA[u] * bflo(vA[u]);
            a1A += wA[u] * bfhi(vA[u]);
            a0B += wB[u] * bflo(vB[u]);
            a1B += wB[u] * bfhi(vB[u]);
        }
        eA = min(nA, e1A);
        eB = min(nB, e1B);
    }
    a0A *= dA; a1A *= dA;
    a0B *= dB; a1B *= dB;
    aggb32[(size_t)iA * 64 + t] = (unsigned)f2bf(a0A) | ((unsigned)f2bf(a1A) << 16);
    if (hasB)
        aggb32[(size_t)iB * 64 + t] = (unsigned)f2bf(a0B) | ((unsigned)f2bf(a1B) << 16);
}

// Fused GRU: 64-row tile per block, 4 waves; wave w owns a 32-col slice and
// ALL 64 rows. Per phase: 16 independent B-loads into REGISTERS (one latency
// round), then 32 LDS A-reads + 64 MFMAs. hq goes to a 3rd LDS buffer.
__global__ __launch_bounds__(256) void gru_fused_kernel(
        const ushort* __restrict__ aggb, const ushort* __restrict__ h0b,
        const ushort* __restrict__ BT, const float* __restrict__ lb2,
        float* __restrict__ hout, int n) {
    __shared__ ushort Aag[64][136];   // agg tile (pad 8 -> 2-way alias, free)
    __shared__ ushort Ah0[64][136];   // h0 tile (bf16)
    __shared__ ushort Ahq[64][136];   // h0*r tile
    int t = threadIdx.x;
    int i0 = blockIdx.x * 64;

    for (int c = t; c < 1024; c += 256) {
        int row = c >> 4, c8 = c & 15;
        size_t gp = (size_t)(i0 + row) * HD + c8 * 8;
        *(short8*)&Aag[row][c8 * 8] = *(const short8*)(aggb + gp);
        *(short8*)&Ah0[row][c8 * 8] = *(const short8*)(h0b + gp);
    }
    __syncthreads();

    int w = t >> 6, lane = t & 63;
    int rlo = lane & 15, koff = (lane >> 4) * 8, rbase = (lane >> 4) * 4;
    int c0 = w * 32;                    // wave's column base within gate

    const f32x4 zero4 = {0.f, 0.f, 0.f, 0.f};
    short8 bfr[2][8];
    f32x4 acc[4][2];
    float zv[4][2][4];

    // ================= phase Z (gate 0) =================
#pragma unroll
    for (int cf = 0; cf < 2; ++cf)
#pragma unroll
        for (int ks = 0; ks < 8; ++ks)
            bfr[cf][ks] = *(const short8*)(BT + (size_t)(c0 + cf * 16 + rlo) * 256
                                           + ks * 32 + koff);
#pragma unroll
    for (int rf = 0; rf < 4; ++rf) { acc[rf][0] = zero4; acc[rf][1] = zero4; }
#pragma unroll
    for (int rf = 0; rf < 4; ++rf)
#pragma unroll
        for (int ks = 0; ks < 8; ++ks) {
            short8 af = (ks < 4)
                ? *(const short8*)&Aag[rf * 16 + rlo][ks * 32 + koff]
                : *(const short8*)&Ah0[rf * 16 + rlo][(ks - 4) * 32 + koff];
            acc[rf][0] = __builtin_amdgcn_mfma_f32_16x16x32_bf16(af, bfr[0][ks], acc[rf][0], 0, 0, 0);
            acc[rf][1] = __builtin_amdgcn_mfma_f32_16x16x32_bf16(af, bfr[1][ks], acc[rf][1], 0, 0, 0);
        }
#pragma unroll
    for (int rf = 0; rf < 4; ++rf)
#pragma unroll
        for (int cf = 0; cf < 2; ++cf) {
            float bv = lb2[c0 + cf * 16 + rlo];
#pragma unroll
            for (int i = 0; i < 4; ++i)
                zv[rf][cf][i] = fast_sigmoid(acc[rf][cf][i] + bv);
        }

    // ================= phase R (gate 1) =================
#pragma unroll
    for (int cf = 0; cf < 2; ++cf)
#pragma unroll
        for (int ks = 0; ks < 8; ++ks)
            bfr[cf][ks] = *(const short8*)(BT + (size_t)(128 + c0 + cf * 16 + rlo) * 256
                                           + ks * 32 + koff);
#pragma unroll
    for (int rf = 0; rf < 4; ++rf) { acc[rf][0] = zero4; acc[rf][1] = zero4; }
#pragma unroll
    for (int rf = 0; rf < 4; ++rf)
#pragma unroll
        for (int ks = 0; ks < 8; ++ks) {
            short8 af = (ks < 4)
                ? *(const short8*)&Aag[rf * 16 + rlo][ks * 32 + koff]
                : *(const short8*)&Ah0[rf * 16 + rlo][(ks - 4) * 32 + koff];
            acc[rf][0] = __builtin_amdgcn_mfma_f32_16x16x32_bf16(af, bfr[0][ks], acc[rf][0], 0, 0, 0);
            acc[rf][1] = __builtin_amdgcn_mfma_f32_16x16x32_bf16(af, bfr[1][ks], acc[rf][1], 0, 0, 0);
        }
#pragma unroll
    for (int rf = 0; rf < 4; ++rf)
#pragma unroll
        for (int cf = 0; cf < 2; ++cf) {
            int lc = c0 + cf * 16 + rlo;
            float bv = lb2[128 + lc];
#pragma unroll
            for (int i = 0; i < 4; ++i) {
                int row = rf * 16 + rbase + i;
                float r = fast_sigmoid(acc[rf][cf][i] + bv);
                Ahq[row][lc] = f2bf(r * bf2f(Ah0[row][lc]));
            }
        }
    __syncthreads();   // hq visible to all waves

    // ================= phase HT (gate 2): A = [agg | hq] =================
#pragma unroll
    for (int cf = 0; cf < 2; ++cf)
#pragma unroll
        for (int ks = 0; ks < 8; ++ks)
            bfr[cf][ks] = *(const short8*)(BT + (size_t)(256 + c0 + cf * 16 + rlo) * 256
                                           + ks * 32 + koff);
#pragma unroll
    for (int rf = 0; rf < 4; ++rf) { acc[rf][0] = zero4; acc[rf][1] = zero4; }
#pragma unroll
    for (int rf = 0; rf < 4; ++rf)
#pragma unroll
        for (int ks = 0; ks < 8; ++ks) {
            short8 af = (ks < 4)
                ? *(const short8*)&Aag[rf * 16 + rlo][ks * 32 + koff]
                : *(const short8*)&Ahq[rf * 16 + rlo][(ks - 4) * 32 + koff];
            acc[rf][0] = __builtin_amdgcn_mfma_f32_16x16x32_bf16(af, bfr[0][ks], acc[rf][0], 0, 0, 0);
            acc[rf][1] = __builtin_amdgcn_mfma_f32_16x16x32_bf16(af, bfr[1][ks], acc[rf][1], 0, 0, 0);
        }
#pragma unroll
    for (int rf = 0; rf < 4; ++rf)
#pragma unroll
        for (int cf = 0; cf < 2; ++cf) {
            int lc = c0 + cf * 16 + rlo;
            float bv = lb2[256 + lc];
#pragma unroll
            for (int i = 0; i < 4; ++i) {
                int row = rf * 16 + rbase + i;
                int grow = i0 + row;
                if (grow < n) {
                    float ht = fast_tanh(acc[rf][cf][i] + bv);
                    float z = zv[rf][cf][i];
                    float h0v = bf2f(Ah0[row][lc]);
                    hout[(size_t)grow * HD + lc] = z * h0v + (1.0f - z) * ht;
                }
            }
        }
}

__global__ __launch_bounds__(128) void pool_kernel(
        const float* __restrict__ hout, const int* __restrict__ nids,
        float* pooled, int U) {
    int t = threadIdx.x;
    float pa = 0.0f;
    for (int u = blockIdx.x; u < U; u += gridDim.x) {
        int nid = nids[u];
        pa += fmaxf(hout[(size_t)nid * HD + t], 0.0f);
    }
    atomicAdd(&pooled[t], pa);
}

__global__ __launch_bounds__(128) void decoder_kernel(
        const float* __restrict__ pooled, float invU,
        const float* __restrict__ linW, const float* __restrict__ linb,
        const float* __restrict__ dnW, const float* __restrict__ dnb,
        const float* __restrict__ outW, const float* __restrict__ outb,
        float* pred, int C) {
    __shared__ float sh[HD];
    int t = threadIdx.x;
    sh[t] = pooled[t] * invU;
    __syncthreads();
    float v = linb[t];
    for (int k = 0; k < HD; ++k) v += sh[k] * linW[k * HD + t];
    __syncthreads();
    sh[t] = v;
    __syncthreads();
    float d = dnb[t];
    for (int k = 0; k < HD; ++k) d += sh[k] * dnW[k * HD + t];
    d = fmaxf(d, 0.0f);
    __syncthreads();
    sh[t] = d;
    __syncthreads();
    if (t < C) {
        float p = outb[t];
        for (int k = 0; k < HD; ++k) p += sh[k] * outW[k * C + t];
        pred[t] = 1.0f / (1.0f + expf(-p));
    }
}

extern "C" void kernel_launch(void* const* d_in, const int* in_sizes, int n_in,
                              void* d_out, int out_size, void* d_ws, size_t ws_size,
                              hipStream_t stream) {
    const float* node_feat = (const float*)d_in[0];
    const float* edge_w    = (const float*)d_in[1];
    const float* h0        = (const float*)d_in[2];
    const float* Wz  = (const float*)d_in[3];  const float* bz  = (const float*)d_in[4];
    const float* Wr  = (const float*)d_in[5];  const float* br  = (const float*)d_in[6];
    const float* Wh  = (const float*)d_in[7];  const float* bh  = (const float*)d_in[8];
    const float* lzW = (const float*)d_in[9];  const float* lzb = (const float*)d_in[10];
    const float* lrW = (const float*)d_in[11]; const float* lrb = (const float*)d_in[12];
    const float* lhW = (const float*)d_in[13]; const float* lhb = (const float*)d_in[14];
    const float* linW= (const float*)d_in[15]; const float* linb= (const float*)d_in[16];
    const float* dnW = (const float*)d_in[17]; const float* dnb = (const float*)d_in[18];
    const float* outW= (const float*)d_in[19]; const float* outb= (const float*)d_in[20];
    const int* src  = (const int*)d_in[21];
    const int* dst  = (const int*)d_in[22];
    const int* nids = (const int*)d_in[23];

    const int N = in_sizes[2] / HD;
    const int E = in_sizes[1];
    const int U = in_sizes[23];
    const int C = in_sizes[20];
    const int NP = (N + 127) & ~127;    // row-padded
    const int NB1K = (N + 1023) / 1024; // scan blocks
    const int NR = (N + RSIZE - 1) / RSIZE;       // ranges
    const int NPAD = NR * RSIZE;
    int NEC = 64;                                  // edge chunks
    {   // keep per-chunk counts < 65536 for packed ushort ranks
        int minc = (E + 65535) / 65536;
        if (NEC < minc) NEC = minc;
    }
    const int EC = (E + NEC - 1) / NEC;

    float* out  = (float*)d_out;
    float* pred = out;          // [C]
    float* hout = out + C;      // [N,H]

    // workspace layout (16B-aligned chunks)
    char* p = (char*)d_ws;
    auto alloc = [&](size_t bytes) { char* r = p; p += (bytes + 15) & ~(size_t)15; return r; };
    float* dinv   = (float*)alloc((size_t)N * 4);
    float* pooled = (float*)alloc(HD * 4);
    int*   counts = (int*)alloc((size_t)N * 4);
    int*   row_ptr= (int*)alloc((size_t)(N + 1) * 4);
    int2*  es     = (int2*)alloc((size_t)E * 8);
    int*   bsums  = (int*)alloc((size_t)1024 * 4);
    int*   pc     = (int*)alloc((size_t)NEC * NPAD * 4);
    float* pw     = (float*)alloc((size_t)NEC * NPAD * 4);
    ushort* nfb   = (ushort*)alloc((size_t)NP * HD * 2);
    ushort* aggb  = (ushort*)alloc((size_t)NP * HD * 2);
    ushort* h0b   = (ushort*)alloc((size_t)NP * HD * 2);
    ushort* BT    = (ushort*)alloc((size_t)3 * 128 * 256 * 2);
    float* lb2    = (float*)alloc(384 * 4);

    hipMemsetAsync(pooled, 0, HD * sizeof(float), stream);

    int prep_items = N * (HD / 8);
    prep_kernel<<<(prep_items + 255) / 256, 256, 0, stream>>>(node_feat, h0, nfb, h0b, N);
    hist_lds_kernel<<<NR * NEC, 256, 0, stream>>>(dst, edge_w, pc, pw, NPAD, NR, EC, E);
    reduce_hist_kernel<<<(N + 255) / 256, 256, 0, stream>>>(pc, pw, counts, dinv,
                                                            NPAD, NEC, N);
    scan_partial_kernel<<<NB1K, 256, 0, stream>>>(counts, bsums, N);
    scan_bsums_kernel<<<1, 1024, 0, stream>>>(bsums, row_ptr + N, NB1K);
    scan_final_kernel<<<NB1K, 256, 0, stream>>>(counts, bsums, row_ptr, N);
    col_scan_kernel<<<(N + 255) / 256, 256, 0, stream>>>(row_ptr, pc, NPAD, NEC, N);
    fill2d_kernel<<<NEC * NR, 512, 0, stream>>>(src, dst, edge_w, dinv, pc,
                                                es, NPAD, NR, EC, E);
    dim3 fg(3, 16);
    fuse_weights_kernel<<<fg, 256, 0, stream>>>(Wz, Wr, Wh, lzW, lrW, lhW, BT);
    lb2_kernel<<<3, 128, 0, stream>>>(lzW, lrW, lhW, bz, br, bh, lzb, lrb, lhb, lb2);
    agg_feat_kernel<<<(N + 7) / 8, 256, 0, stream>>>(
        (const unsigned*)nfb, dinv, row_ptr, es, (unsigned*)aggb, N);
    gru_fused_kernel<<<NP / 64, 256, 0, stream>>>(aggb, h0b, BT, lb2, hout, N);
    pool_kernel<<<512, 128, 0, stream>>>(hout, nids, pooled, U);
    decoder_kernel<<<1, 128, 0, stream>>>(pooled, 1.0f / (float)U,
                                          linW, linb, dnW, dnb, outW, outb, pred, C);
}